// Round 8
// baseline (617.671 us; speedup 1.0000x reference)
//
#include <hip/hip_runtime.h>
#include <math.h>

// Problem constants
#define TOK   4096    // B*N
#define EDIM  512
#define HEADS 8
#define DHEAD 64
#define GCOLS 32768   // H*D*D

typedef unsigned short u16;
typedef _Float16 f16;
typedef __attribute__((ext_vector_type(8))) f16 f16x8;      // 8 fp16 = 4 VGPRs (MFMA A/B frag)
typedef __attribute__((ext_vector_type(4))) f16 f16x4;
typedef __attribute__((ext_vector_type(4))) float f32x4;    // MFMA C/D frag
typedef __attribute__((ext_vector_type(4))) unsigned short u16x4;

typedef const __attribute__((address_space(1))) void* gas_ptr;
typedef __attribute__((address_space(3))) void* las_ptr;

__device__ __forceinline__ void gll16(const void* g, void* lds) {
  // async global->LDS, 16B/lane: per-lane global addr, wave-uniform LDS base,
  // lane i lands at lds + i*16
  __builtin_amdgcn_global_load_lds((gas_ptr)g, (las_ptr)lds, 16, 0, 0);
}

// Counted vmem wait: lets prefetch loads stay in flight across barriers.
#define WAITV(N) asm volatile("s_waitcnt vmcnt(" #N ")" ::: "memory")
// Raw barrier WITHOUT the implicit vmcnt(0) drain __syncthreads emits.
__device__ __forceinline__ void barrier_raw() { asm volatile("s_barrier" ::: "memory"); }

__device__ __forceinline__ u16 f2h_bits(float f) {
  union { f16 h; u16 u; } v; v.h = (f16)f;   // RNE
  return v.u;
}

// Abramowitz-Stegun 7.1.26 erf: |abs err| <= 1.5e-7, ~14 VALU insts.
__device__ __forceinline__ float fast_gelu(float x) {
  float s = x * 0.7071067811865475f;
  float ax = fabsf(s);
  float t = __builtin_amdgcn_rcpf(1.0f + 0.3275911f * ax);
  float poly = t * (0.254829592f + t * (-0.284496736f + t * (1.421413741f +
               t * (-1.453152027f + t * 1.061405429f))));
  float e = __expf(-ax * ax);
  float r = 1.0f - poly * e;
  float erfv = copysignf(r, s);
  return 0.5f * x * (1.0f + erfv);
}

// ---------------------------------------------------------------- cast x -> fp16
__global__ void cast_f16_k(const float* __restrict__ in, u16* __restrict__ out, int n) {
  int i = (blockIdx.x * blockDim.x + threadIdx.x) * 4;
  if (i + 3 < n) {
    float4 f = *(const float4*)(in + i);
    u16x4 h;
    h.x = f2h_bits(f.x); h.y = f2h_bits(f.y);
    h.z = f2h_bits(f.z); h.w = f2h_bits(f.w);
    *(u16x4*)(out + i) = h;
  }
}

// -------------------- transpose W[K][N] -> Wt[N][K] fp16
__global__ void transpose_f16_k(const float* __restrict__ in, u16* __restrict__ out,
                                int K, int N) {
  __shared__ float tile[32][33];
  int n0 = blockIdx.x * 32, k0 = blockIdx.y * 32;
  int tx = threadIdx.x, ty = threadIdx.y;  // (32,8)
  #pragma unroll
  for (int i = 0; i < 4; i++)
    tile[ty + i * 8][tx] = in[(size_t)(k0 + ty + i * 8) * N + n0 + tx];
  __syncthreads();
  #pragma unroll
  for (int i = 0; i < 4; i++)
    out[(size_t)(n0 + ty + i * 8) * K + k0 + tx] = f2h_bits(tile[tx][ty + i * 8]);
}

// ---------------------------------------------------------------- QKV GEMM
// 128x128 tile, BK=64, 4 waves (each 64x64), fp16 MFMA.
// v3: double-buffer + prefetch + COUNTED vmcnt(8) with raw s_barrier.
__global__ __launch_bounds__(256, 2) void qkv_gemm_k(
    const u16* __restrict__ xf, const u16* __restrict__ Wqt,
    const u16* __restrict__ Wkt, const u16* __restrict__ Wvt,
    const float* __restrict__ bq, const float* __restrict__ bk, const float* __restrict__ bv,
    u16* __restrict__ qho, u16* __restrict__ ko, u16* __restrict__ vTo) {
  __shared__ __align__(16) u16 As[2][16 * 512];   // 2 x 16KB
  __shared__ __align__(16) u16 Bs[2][16 * 512];   // 2 x 16KB  -> 64KB, 2 blk/CU
  const int which = blockIdx.z;
  const u16* Wt = which == 0 ? Wqt : (which == 1 ? Wkt : Wvt);
  const float* bias = which == 0 ? bq : (which == 1 ? bk : bv);
  const int m0 = blockIdx.x * 128;
  const int n0 = blockIdx.y * 128;
  const int tid = threadIdx.x;
  const int w = tid >> 6, lane = tid & 63, l15 = lane & 15, quad = lane >> 4;
  const int mhalf = w >> 1, nhalf = w & 1;

  f32x4 acc[4][4];
  #pragma unroll
  for (int i = 0; i < 4; i++)
    #pragma unroll
    for (int j = 0; j < 4; j++) acc[i][j] = f32x4{0.f, 0.f, 0.f, 0.f};

  auto stage = [&](int d, int kk) {
    #pragma unroll
    for (int i = 0; i < 8; i++) {
      int cb = w * 8 + i;
      if (cb < 16) {
        int ks = cb >> 3, mt = cb & 7;
        gll16(xf + (size_t)(m0 + mt * 16 + l15) * 512 + kk + ks * 32 + quad * 8,
              As[d] + cb * 512);
      } else {
        int bi = cb - 16, ks = bi >> 3, nt = bi & 7;
        gll16(Wt + (size_t)(n0 + nt * 16 + l15) * 512 + kk + ks * 32 + quad * 8,
              Bs[d] + bi * 512);
      }
    }
  };

  stage(0, 0);                     // 8 loads/wave in flight
  int cur = 0;
  for (int kt = 0; kt < 8; kt++) {
    if (kt < 7) { stage(cur ^ 1, (kt + 1) * 64); WAITV(8); }  // keep prefetch in flight
    else        { WAITV(0); }
    barrier_raw();                 // all waves' stage-kt data resident
    const u16* Asb = As[cur];
    const u16* Bsb = Bs[cur];
    #pragma unroll
    for (int ks = 0; ks < 2; ks++) {
      f16x8 a[4], b[4];
      #pragma unroll
      for (int mt = 0; mt < 4; mt++)
        a[mt] = *(const f16x8*)(Asb + (ks * 8 + mhalf * 4 + mt) * 512 + lane * 8);
      #pragma unroll
      for (int nt = 0; nt < 4; nt++)
        b[nt] = *(const f16x8*)(Bsb + (ks * 8 + nhalf * 4 + nt) * 512 + lane * 8);
      #pragma unroll
      for (int mt = 0; mt < 4; mt++)
        #pragma unroll
        for (int nt = 0; nt < 4; nt++)
          acc[mt][nt] = __builtin_amdgcn_mfma_f32_16x16x32_f16(a[mt], b[nt], acc[mt][nt], 0, 0, 0);
    }
    barrier_raw();                 // protect buf[cur] before next iter's stage()
    cur ^= 1;
  }
  #pragma unroll
  for (int nt = 0; nt < 4; nt++) {
    int col = n0 + (nhalf * 4 + nt) * 16 + l15;
    float bia = bias[col];
    int h = col >> 6, d = col & 63;
    #pragma unroll
    for (int mt = 0; mt < 4; mt++) {
      #pragma unroll
      for (int r = 0; r < 4; r++) {
        int t = m0 + (mhalf * 4 + mt) * 16 + quad * 4 + r;
        int b_ = t >> 10, n = t & 1023;
        float val = acc[mt][nt][r] + bia;
        size_t idx = (((size_t)(b_ * 8 + h) * 1024) + n) * 64 + d;
        if (which == 0)      qho[idx] = f2h_bits(val);
        else if (which == 1) ko[idx] = f2h_bits(val);
        else                 vTo[(((size_t)(b_ * 8 + h) * 64) + d) * 1024 + n] = f2h_bits(val);
      }
    }
  }
}

// ---------------------------------------------------------------- fused g-GEMM + q.g
// v8: v7 structure (m97 replica: 128x128 tile, single-buffered 32KB union,
// full-drain __syncthreads per stage, XCD-pinned Wgt panels) with the SPILL
// REMOVED: __launch_bounds__(256,3) -> VGPR cap ~170, fits the ~155-reg live
// set (acc 64 + qgacc 64 + frags + addr; m97 = 164 VGPR at same 3 waves/SIMD).
// 3 blocks/CU cover each other's drains (m114). v7's (256,4) capped at 128
// VGPR -> accumulators spilled to scratch (WRITE 384MB, FETCH 400MB, 12.6%
// MfmaUtil) -- that experiment never tested occupancy at all.
__global__ __launch_bounds__(256, 3) void qg_fused_k(
    const u16* __restrict__ xf, const u16* __restrict__ Wgt,
    const u16* __restrict__ bgh, const u16* __restrict__ qh,
    float* __restrict__ qgp) {
  __shared__ __align__(16) u16 ABs[32 * 512];     // 32KB: A blocks 0-15, B blocks 16-31
  __shared__ __align__(16) f16 Qs[128 * 16];      // 4KB: q rows, this d-quarter
  __shared__ __align__(16) f16 bgs[16 * 64];      // 2KB: bias, this (head,dq)
  u16* As = ABs;
  u16* Bs = ABs + 16 * 512;
  const int bid = blockIdx.x;
  const int dq = bid & 3, head = (bid >> 2) & 7;
  const int t0 = (bid >> 5) * 128;
  const int tid = threadIdx.x;
  const int w = tid >> 6, lane = tid & 63, l15 = lane & 15, quad = lane >> 4;
  const int mhalf = w >> 1, nhalf = w & 1;
  const int b_ = t0 >> 10, nseq0 = t0 & 1023;
  const int bh = b_ * 8 + head;
  const u16* qbase = qh + (((size_t)bh * 1024) + nseq0) * 64;

  // prologue: 6 jobs (0-3 Qs quarters, 4-5 bgs halves); drained by the first
  // __syncthreads. Non-uniform counts are fine with drain-style waits.
  #pragma unroll
  for (int i = 0; i < 2; i++) {
    int job = w * 2 + i;
    if (job < 4) {
      // Qs rows job*32..+32, 16 d-cols: lane -> row (lane>>1), half (lane&1)
      gll16(qbase + (size_t)(job * 32 + (lane >> 1)) * 64 + dq * 16 + (lane & 1) * 8,
            (f16*)Qs + job * 512);
    } else if (job < 6) {
      int j = job - 4;
      gll16(bgh + (size_t)head * 4096 + (dq * 16 + j * 8 + (lane >> 3)) * 64 + (lane & 7) * 8,
            (f16*)bgs + j * 512);
    }
  }

  // Per stage: A 16 blocks (4/wave) + B 16 blocks (4/wave) = 8 gll16/wave.
  auto stage = [&](int s) {
    int jp = s >> 3, kk = (s & 7) << 6;
    const u16* bsrc = Wgt + (size_t)(head * 4096 + (dq * 16 + jp * 2) * 64) * 512;
    #pragma unroll
    for (int i = 0; i < 4; i++) {
      int cb = w * 4 + i, ks = cb >> 3, mt = cb & 7;
      gll16(xf + (size_t)(t0 + mt * 16 + l15) * 512 + kk + ks * 32 + quad * 8,
            As + cb * 512);
    }
    #pragma unroll
    for (int i = 0; i < 4; i++) {
      int bi = w * 4 + i, ks = bi >> 3, nt = bi & 7;
      gll16(bsrc + (size_t)(nt * 16 + l15) * 512 + kk + ks * 32 + quad * 8,
            Bs + bi * 512);
    }
  };

  f32x4 acc[4][4], qgacc[4][4];
  #pragma unroll
  for (int i = 0; i < 4; i++)
    #pragma unroll
    for (int j = 0; j < 4; j++) {
      acc[i][j] = f32x4{0.f, 0.f, 0.f, 0.f};
      qgacc[i][j] = f32x4{0.f, 0.f, 0.f, 0.f};
    }

  for (int s = 0; s < 64; s++) {
    stage(s);
    __syncthreads();               // full drain + barrier: tile resident
    #pragma unroll
    for (int ks = 0; ks < 2; ks++) {
      f16x8 a[4];
      #pragma unroll
      for (int mt = 0; mt < 4; mt++)
        a[mt] = *(const f16x8*)(As + (ks * 8 + mhalf * 4 + mt) * 512 + lane * 8);
      #pragma unroll
      for (int nt = 0; nt < 4; nt++) {
        // b loaded per-nt (not staged x4) to keep peak VGPR pressure down
        f16x8 b = *(const f16x8*)(Bs + (ks * 8 + nhalf * 4 + nt) * 512 + lane * 8);
        #pragma unroll
        for (int mt = 0; mt < 4; mt++)
          acc[mt][nt] = __builtin_amdgcn_mfma_f32_16x16x32_f16(a[mt], b, acc[mt][nt], 0, 0, 0);
      }
    }
    if ((s & 7) == 7) {
      // epilogue for j-pair jp: this wave's d = dq*16 + jp*2 + nhalf.
      int jp = s >> 3;
      int dloc = jp * 2 + nhalf;
      float bgv[4];
      #pragma unroll
      for (int nt = 0; nt < 4; nt++)
        bgv[nt] = (float)bgs[dloc * 64 + nt * 16 + l15];
      #pragma unroll
      for (int mt = 0; mt < 4; mt++) {
        #pragma unroll
        for (int r = 0; r < 4; r++) {
          int row = mhalf * 64 + mt * 16 + quad * 4 + r;
          float qv = (float)Qs[row * 16 + dloc];   // broadcast within quad
          #pragma unroll
          for (int nt = 0; nt < 4; nt++)
            qgacc[mt][nt][r] += qv * fast_gelu(acc[mt][nt][r] + bgv[nt]);
        }
      }
      #pragma unroll
      for (int i = 0; i < 4; i++)
        #pragma unroll
        for (int j = 0; j < 4; j++) acc[i][j] = f32x4{0.f, 0.f, 0.f, 0.f};
    }
    __syncthreads();               // reads done before next stage overwrites
  }
  // cross-nhalf reduction (both nhalf waves hold full [tok][e] partial grids)
  float* red = (float*)ABs;        // 32KB = 128 x 64 floats; all loads drained
  if (nhalf == 1) {
    #pragma unroll
    for (int mt = 0; mt < 4; mt++)
      #pragma unroll
      for (int r = 0; r < 4; r++) {
        int tok = mhalf * 64 + mt * 16 + quad * 4 + r;
        #pragma unroll
        for (int nt = 0; nt < 4; nt++)
          red[tok * 64 + nt * 16 + l15] = qgacc[mt][nt][r];
      }
  }
  __syncthreads();
  if (nhalf == 0) {
    float* outp = qgp + ((size_t)dq * 32 + bh) * 1024 * 64;
    #pragma unroll
    for (int mt = 0; mt < 4; mt++)
      #pragma unroll
      for (int r = 0; r < 4; r++) {
        int tok = mhalf * 64 + mt * 16 + quad * 4 + r;
        int n = nseq0 + tok;
        #pragma unroll
        for (int nt = 0; nt < 4; nt++)
          outp[(size_t)n * 64 + nt * 16 + l15] =
              qgacc[mt][nt][r] + red[tok * 64 + nt * 16 + l15];
      }
  }
}

// ---------------------------------------------------------------- flash attention
// Block = (b,h,qtile64), 4 waves x 16 q-rows. qg = sum of 4 fp32 d-split
// partials (one-time per block); counted vmcnt(4) + raw barriers.
__global__ __launch_bounds__(256, 2) void attn_k(
    const float* __restrict__ qgp, const u16* __restrict__ kb,
    const u16* __restrict__ vTb, float* __restrict__ out) {
  __shared__ __align__(16) u16 Ks[2][8 * 512];
  __shared__ __align__(16) u16 Vs[2][8 * 512];
  __shared__ __align__(16) f16 Ps[4][16 * 72];    // per-wave P, row stride 72
  const int idx = blockIdx.x;
  const int bh = idx & 31;   // b*8+h -> XCD = bh%8
  const int qt = idx >> 5;
  const int b_ = bh >> 3, h = bh & 7;
  const int tid = threadIdx.x;
  const int w = tid >> 6, lane = tid & 63, l15 = lane & 15, quad = lane >> 4;

  const float* qgB = qgp + (size_t)bh * 1024 * 64;
  const size_t PS = (size_t)32 * 1024 * 64;       // partial stride (2M floats)
  const u16* kB  = kb  + (size_t)bh * 1024 * 64;
  const u16* vB  = vTb + (size_t)bh * 64 * 1024;

  f16x8 aq[2];
  #pragma unroll
  for (int ks = 0; ks < 2; ks++) {
    size_t off = (size_t)(qt * 64 + w * 16 + l15) * 64 + ks * 32 + quad * 8;
    f16x8 v;
    #pragma unroll
    for (int e = 0; e < 8; e++)
      v[e] = (f16)(qgB[off + e] + qgB[PS + off + e] +
                   qgB[2 * PS + off + e] + qgB[3 * PS + off + e]);
    aq[ks] = v;
  }

  f32x4 o[4];
  #pragma unroll
  for (int i = 0; i < 4; i++) o[i] = f32x4{0.f, 0.f, 0.f, 0.f};
  float m_old[4], l_old[4];
  #pragma unroll
  for (int r = 0; r < 4; r++) { m_old[r] = -1e30f; l_old[r] = 0.f; }

  auto stageKV = [&](int d, int kt) {
    #pragma unroll
    for (int i = 0; i < 2; i++) {
      int cb = w * 2 + i;
      int ks = cb >> 2, nt = cb & 3;
      gll16(kB + (size_t)(kt * 64 + nt * 16 + l15) * 64 + ks * 32 + quad * 8, Ks[d] + cb * 512);
      gll16(vB + (size_t)(nt * 16 + l15) * 1024 + kt * 64 + ks * 32 + quad * 8, Vs[d] + cb * 512);
    }
  };

  stageKV(0, 0);                   // 4 loads/wave in flight
  int cur = 0;
  for (int kt = 0; kt < 16; kt++) {
    if (kt < 15) { stageKV(cur ^ 1, kt + 1); WAITV(4); }
    else         { WAITV(0); }
    barrier_raw();
    f32x4 s[4];
    #pragma unroll
    for (int nt = 0; nt < 4; nt++) s[nt] = f32x4{0.f, 0.f, 0.f, 0.f};
    #pragma unroll
    for (int ks = 0; ks < 2; ks++)
      #pragma unroll
      for (int nt = 0; nt < 4; nt++) {
        f16x8 kf = *(const f16x8*)(Ks[cur] + (ks * 4 + nt) * 512 + lane * 8);
        s[nt] = __builtin_amdgcn_mfma_f32_16x16x32_f16(aq[ks], kf, s[nt], 0, 0, 0);
      }
    float rmax[4];
    #pragma unroll
    for (int r = 0; r < 4; r++)
      rmax[r] = fmaxf(fmaxf(s[0][r], s[1][r]), fmaxf(s[2][r], s[3][r]));
    #pragma unroll
    for (int off = 1; off < 16; off <<= 1)
      #pragma unroll
      for (int r = 0; r < 4; r++)
        rmax[r] = fmaxf(rmax[r], __shfl_xor(rmax[r], off));
    float alpha[4], rsum[4];
    #pragma unroll
    for (int r = 0; r < 4; r++) {
      float mn = fmaxf(m_old[r], rmax[r]);
      alpha[r] = __expf(m_old[r] - mn);
      m_old[r] = mn;
      rsum[r] = 0.f;
    }
    #pragma unroll
    for (int nt = 0; nt < 4; nt++)
      #pragma unroll
      for (int r = 0; r < 4; r++) {
        float p = __expf(s[nt][r] - m_old[r]);
        rsum[r] += p;
        Ps[w][(quad * 4 + r) * 72 + nt * 16 + l15] = (f16)p;
      }
    #pragma unroll
    for (int off = 1; off < 16; off <<= 1)
      #pragma unroll
      for (int r = 0; r < 4; r++)
        rsum[r] += __shfl_xor(rsum[r], off);
    #pragma unroll
    for (int r = 0; r < 4; r++) l_old[r] = l_old[r] * alpha[r] + rsum[r];
    #pragma unroll
    for (int nt = 0; nt < 4; nt++)
      #pragma unroll
      for (int r = 0; r < 4; r++) o[nt][r] *= alpha[r];
    #pragma unroll
    for (int ks = 0; ks < 2; ks++) {
      f16x8 pa = *(const f16x8*)(&Ps[w][l15 * 72 + ks * 32 + quad * 8]);
      #pragma unroll
      for (int nt = 0; nt < 4; nt++) {
        f16x8 vf = *(const f16x8*)(Vs[cur] + (ks * 4 + nt) * 512 + lane * 8);
        o[nt] = __builtin_amdgcn_mfma_f32_16x16x32_f16(pa, vf, o[nt], 0, 0, 0);
      }
    }
    barrier_raw();                 // protect Ks/Vs[cur] before next stageKV
    cur ^= 1;
  }
  #pragma unroll
  for (int r = 0; r < 4; r++) {
    float inv = 1.f / l_old[r];
    int n = qt * 64 + w * 16 + quad * 4 + r;
    #pragma unroll
    for (int nt = 0; nt < 4; nt++)
      out[((size_t)(b_ * 1024 + n)) * 512 + h * 64 + nt * 16 + l15] = o[nt][r] * inv;
  }
}

// ----------------------------------------------------------------------- host
extern "C" void kernel_launch(void* const* d_in, const int* in_sizes, int n_in,
                              void* d_out, int out_size, void* d_ws, size_t ws_size,
                              hipStream_t stream) {
  const float* x  = (const float*)d_in[0];
  const float* Wq = (const float*)d_in[1];
  const float* bq = (const float*)d_in[2];
  const float* Wk = (const float*)d_in[3];
  const float* bk = (const float*)d_in[4];
  const float* Wv = (const float*)d_in[5];
  const float* bv = (const float*)d_in[6];
  const float* Wg = (const float*)d_in[7];
  const float* bg = (const float*)d_in[8];
  float* out = (float*)d_out;

  const size_t NX = (size_t)TOK * EDIM;        // 2M elems
  const size_t NWG = (size_t)GCOLS * EDIM;     // 16.8M elems
  const size_t NW = (size_t)EDIM * EDIM;       // 256K elems

  char* p = (char*)d_ws;
  u16* xf  = (u16*)p; p += NX * 2;             // x fp16
  u16* Wgt = (u16*)p; p += NWG * 2;            // Wg^T fp16 (33.5 MB)
  u16* Wqt = (u16*)p; p += NW * 2;
  u16* Wkt = (u16*)p; p += NW * 2;
  u16* Wvt = (u16*)p; p += NW * 2;
  u16* qh  = (u16*)p; p += NX * 2;             // q fp16 [B][H][N][D]
  u16* kf  = (u16*)p; p += NX * 2;             // k fp16
  u16* vT  = (u16*)p; p += NX * 2;             // v^T fp16
  float* qgp = (float*)p; p += NX * 4 * 4;     // qg fp32 partials [4][B*H][N][D] (32MB)
  u16* bgh = (u16*)p; p += GCOLS * 2;          // bg fp16 (64KB)

  hipLaunchKernelGGL(cast_f16_k, dim3(NX / 1024), dim3(256), 0, stream,
                     x, xf, (int)NX);
  hipLaunchKernelGGL(cast_f16_k, dim3(GCOLS / 1024), dim3(256), 0, stream,
                     bg, bgh, GCOLS);
  hipLaunchKernelGGL(transpose_f16_k, dim3(EDIM / 32, EDIM / 32), dim3(32, 8), 0, stream,
                     Wq, Wqt, EDIM, EDIM);
  hipLaunchKernelGGL(transpose_f16_k, dim3(EDIM / 32, EDIM / 32), dim3(32, 8), 0, stream,
                     Wk, Wkt, EDIM, EDIM);
  hipLaunchKernelGGL(transpose_f16_k, dim3(EDIM / 32, EDIM / 32), dim3(32, 8), 0, stream,
                     Wv, Wvt, EDIM, EDIM);
  hipLaunchKernelGGL(transpose_f16_k, dim3(GCOLS / 32, EDIM / 32), dim3(32, 8), 0, stream,
                     Wg, Wgt, EDIM, GCOLS);
  hipLaunchKernelGGL(qkv_gemm_k, dim3(TOK / 128, EDIM / 128, 3), dim3(256), 0, stream,
                     xf, Wqt, Wkt, Wvt, bq, bk, bv, qh, kf, vT);
  hipLaunchKernelGGL(qg_fused_k, dim3(1024), dim3(256), 0, stream,
                     xf, Wgt, bgh, qh, qgp);
  hipLaunchKernelGGL(attn_k, dim3(512), dim3(256), 0, stream,
                     qgp, kf, vT, out);
}

// Round 9
// 507.086 us; speedup vs baseline: 1.2181x; 1.2181x over previous
//
#include <hip/hip_runtime.h>
#include <math.h>

// Problem constants
#define TOK   4096    // B*N
#define EDIM  512
#define HEADS 8
#define DHEAD 64
#define GCOLS 32768   // H*D*D

typedef unsigned short u16;
typedef _Float16 f16;
typedef __attribute__((ext_vector_type(8))) f16 f16x8;      // 8 fp16 = 4 VGPRs (MFMA A/B frag)
typedef __attribute__((ext_vector_type(4))) f16 f16x4;
typedef __attribute__((ext_vector_type(4))) float f32x4;    // MFMA C/D frag
typedef __attribute__((ext_vector_type(4))) unsigned short u16x4;

typedef const __attribute__((address_space(1))) void* gas_ptr;
typedef __attribute__((address_space(3))) void* las_ptr;

__device__ __forceinline__ void gll16(const void* g, void* lds) {
  // async global->LDS, 16B/lane: per-lane global addr, wave-uniform LDS base,
  // lane i lands at lds + i*16
  __builtin_amdgcn_global_load_lds((gas_ptr)g, (las_ptr)lds, 16, 0, 0);
}

// Counted vmem wait: lets prefetch loads stay in flight across barriers.
#define WAITV(N) asm volatile("s_waitcnt vmcnt(" #N ")" ::: "memory")
// Raw barrier WITHOUT the implicit vmcnt(0) drain __syncthreads emits.
__device__ __forceinline__ void barrier_raw() { asm volatile("s_barrier" ::: "memory"); }

__device__ __forceinline__ u16 f2h_bits(float f) {
  union { f16 h; u16 u; } v; v.h = (f16)f;   // RNE
  return v.u;
}

// Abramowitz-Stegun 7.1.26 erf: |abs err| <= 1.5e-7, ~14 VALU insts.
__device__ __forceinline__ float fast_gelu(float x) {
  float s = x * 0.7071067811865475f;
  float ax = fabsf(s);
  float t = __builtin_amdgcn_rcpf(1.0f + 0.3275911f * ax);
  float poly = t * (0.254829592f + t * (-0.284496736f + t * (1.421413741f +
               t * (-1.453152027f + t * 1.061405429f))));
  float e = __expf(-ax * ax);
  float r = 1.0f - poly * e;
  float erfv = copysignf(r, s);
  return 0.5f * x * (1.0f + erfv);
}

// ---------------------------------------------------------------- cast x -> fp16
__global__ void cast_f16_k(const float* __restrict__ in, u16* __restrict__ out, int n) {
  int i = (blockIdx.x * blockDim.x + threadIdx.x) * 4;
  if (i + 3 < n) {
    float4 f = *(const float4*)(in + i);
    u16x4 h;
    h.x = f2h_bits(f.x); h.y = f2h_bits(f.y);
    h.z = f2h_bits(f.z); h.w = f2h_bits(f.w);
    *(u16x4*)(out + i) = h;
  }
}

// -------------------- transpose W[K][N] -> Wt[N][K] fp16
__global__ void transpose_f16_k(const float* __restrict__ in, u16* __restrict__ out,
                                int K, int N) {
  __shared__ float tile[32][33];
  int n0 = blockIdx.x * 32, k0 = blockIdx.y * 32;
  int tx = threadIdx.x, ty = threadIdx.y;  // (32,8)
  #pragma unroll
  for (int i = 0; i < 4; i++)
    tile[ty + i * 8][tx] = in[(size_t)(k0 + ty + i * 8) * N + n0 + tx];
  __syncthreads();
  #pragma unroll
  for (int i = 0; i < 4; i++)
    out[(size_t)(n0 + ty + i * 8) * K + k0 + tx] = f2h_bits(tile[tx][ty + i * 8]);
}

// ---------------------------------------------------------------- QKV GEMM
// 128x128 tile, BK=64, 4 waves (each 64x64), fp16 MFMA.
// v3: double-buffer + prefetch + COUNTED vmcnt(8) with raw s_barrier.
__global__ __launch_bounds__(256, 2) void qkv_gemm_k(
    const u16* __restrict__ xf, const u16* __restrict__ Wqt,
    const u16* __restrict__ Wkt, const u16* __restrict__ Wvt,
    const float* __restrict__ bq, const float* __restrict__ bk, const float* __restrict__ bv,
    u16* __restrict__ qho, u16* __restrict__ ko, u16* __restrict__ vTo) {
  __shared__ __align__(16) u16 As[2][16 * 512];   // 2 x 16KB
  __shared__ __align__(16) u16 Bs[2][16 * 512];   // 2 x 16KB  -> 64KB, 2 blk/CU
  const int which = blockIdx.z;
  const u16* Wt = which == 0 ? Wqt : (which == 1 ? Wkt : Wvt);
  const float* bias = which == 0 ? bq : (which == 1 ? bk : bv);
  const int m0 = blockIdx.x * 128;
  const int n0 = blockIdx.y * 128;
  const int tid = threadIdx.x;
  const int w = tid >> 6, lane = tid & 63, l15 = lane & 15, quad = lane >> 4;
  const int mhalf = w >> 1, nhalf = w & 1;

  f32x4 acc[4][4];
  #pragma unroll
  for (int i = 0; i < 4; i++)
    #pragma unroll
    for (int j = 0; j < 4; j++) acc[i][j] = f32x4{0.f, 0.f, 0.f, 0.f};

  auto stage = [&](int d, int kk) {
    #pragma unroll
    for (int i = 0; i < 8; i++) {
      int cb = w * 8 + i;
      if (cb < 16) {
        int ks = cb >> 3, mt = cb & 7;
        gll16(xf + (size_t)(m0 + mt * 16 + l15) * 512 + kk + ks * 32 + quad * 8,
              As[d] + cb * 512);
      } else {
        int bi = cb - 16, ks = bi >> 3, nt = bi & 7;
        gll16(Wt + (size_t)(n0 + nt * 16 + l15) * 512 + kk + ks * 32 + quad * 8,
              Bs[d] + bi * 512);
      }
    }
  };

  stage(0, 0);                     // 8 loads/wave in flight
  int cur = 0;
  for (int kt = 0; kt < 8; kt++) {
    if (kt < 7) { stage(cur ^ 1, (kt + 1) * 64); WAITV(8); }  // keep prefetch in flight
    else        { WAITV(0); }
    barrier_raw();                 // all waves' stage-kt data resident
    const u16* Asb = As[cur];
    const u16* Bsb = Bs[cur];
    #pragma unroll
    for (int ks = 0; ks < 2; ks++) {
      f16x8 a[4], b[4];
      #pragma unroll
      for (int mt = 0; mt < 4; mt++)
        a[mt] = *(const f16x8*)(Asb + (ks * 8 + mhalf * 4 + mt) * 512 + lane * 8);
      #pragma unroll
      for (int nt = 0; nt < 4; nt++)
        b[nt] = *(const f16x8*)(Bsb + (ks * 8 + nhalf * 4 + nt) * 512 + lane * 8);
      #pragma unroll
      for (int mt = 0; mt < 4; mt++)
        #pragma unroll
        for (int nt = 0; nt < 4; nt++)
          acc[mt][nt] = __builtin_amdgcn_mfma_f32_16x16x32_f16(a[mt], b[nt], acc[mt][nt], 0, 0, 0);
    }
    barrier_raw();                 // protect buf[cur] before next iter's stage()
    cur ^= 1;
  }
  #pragma unroll
  for (int nt = 0; nt < 4; nt++) {
    int col = n0 + (nhalf * 4 + nt) * 16 + l15;
    float bia = bias[col];
    int h = col >> 6, d = col & 63;
    #pragma unroll
    for (int mt = 0; mt < 4; mt++) {
      #pragma unroll
      for (int r = 0; r < 4; r++) {
        int t = m0 + (mhalf * 4 + mt) * 16 + quad * 4 + r;
        int b_ = t >> 10, n = t & 1023;
        float val = acc[mt][nt][r] + bia;
        size_t idx = (((size_t)(b_ * 8 + h) * 1024) + n) * 64 + d;
        if (which == 0)      qho[idx] = f2h_bits(val);
        else if (which == 1) ko[idx] = f2h_bits(val);
        else                 vTo[(((size_t)(b_ * 8 + h) * 64) + d) * 1024 + n] = f2h_bits(val);
      }
    }
  }
}

// ---------------------------------------------------------------- fused g-GEMM + q.g
// v9: v3's register-lean tile/wave layout (128 tok x 256 cols/stage, 8 waves,
// 32 MFMA/wave/stage, 4-d j-groups, qg state = 16 floats/thread) split in
// d-HALVES: 32 d's -> 8 jp x 8 kk = 64 stages/block, grid 512 (8 heads x
// 2 dh x 32 t-tiles, head-pinned XCD). SINGLE-buffered LDS: As 16K + Bs 32K
// + Qs 8K + bgs 4K = 60KB -> 2 blocks/CU; m97 drain schedule (stage -> sync
// -> body -> sync): the two independent barrier domains cover each other's
// drains (m114). Per-CU stage/MFMA/load totals identical to v3; the ONLY
// change vs v3 is occupancy. v8's version of this test was confounded by the
// fat qgacc layout (AGPR 128 + spill); this layout measured 108 VGPR in v3.
// Output: fp32 d-half partial, summed in attn (R0-proven).
__global__ __launch_bounds__(512, 4) void qg_fused_k(
    const u16* __restrict__ xf, const u16* __restrict__ Wgt,
    const u16* __restrict__ bgh, const u16* __restrict__ qh,
    float* __restrict__ qgp) {
  __shared__ __align__(16) u16 As[16 * 512];      // 16KB: 128 tok x 64 K
  __shared__ __align__(16) u16 Bs[32 * 512];      // 32KB: 256 cols x 64 K
  __shared__ __align__(16) f16 Qs[128 * 32];      // 8KB: q rows, this d-half
  __shared__ __align__(16) f16 bgs[32 * 64];      // 4KB: bg, this (head,dh)
  const int bid = blockIdx.x;
  const int head = bid & 7;                       // XCD-pinned per head
  const int dh = (bid >> 3) & 1;                  // d-half
  const int t0 = (bid >> 4) * 128;
  const int tid = threadIdx.x;
  const int w = tid >> 6, lane = tid & 63, l15 = lane & 15, quad = lane >> 4;
  const int mhalf = w >> 2;   // 0..1  (token half)
  const int ntA = w & 3;      // 0..3  (e-range /16)
  const int b_ = t0 >> 10, nseq0 = t0 & 1023;
  const int bh = b_ * 8 + head;
  const u16* qbase = qh + (((size_t)bh * 1024) + nseq0) * 64;

  // prologue: 2 loads/wave (uniform). Qs: 128 rows x 32 d fp16 (8 gll16);
  // bgs: 32 d x 64 e fp16 (4 gll16, waves 4-7 duplicate -- same data+dest).
  {
    // Qs chunk w: lane l -> row w*16 + (l>>2), d-col (l&3)*8
    gll16(qbase + (size_t)(w * 16 + (lane >> 2)) * 64 + dh * 32 + (lane & 3) * 8,
          (f16*)Qs + w * 512);
    // bgs chunk c=w&3: lane l -> d_local c*8 + (l>>3), e (l&7)*8
    int c = w & 3;
    gll16(bgh + (size_t)head * 4096 + (size_t)(dh * 32 + c * 8 + (lane >> 3)) * 64 + (lane & 7) * 8,
          (f16*)bgs + c * 512);
  }

  // Per stage: A 16 blocks + B 32 blocks = 48, 6 gll16/wave (same as v3).
  auto stage = [&](int s) {
    int jp = s >> 3, kk = (s & 7) << 6;
    int c0 = head * 4096 + (dh * 32 + jp * 4) * 64;  // 256 cols = 4 d's x 64 e
    #pragma unroll
    for (int i = 0; i < 6; i++) {
      int cb = w * 6 + i;
      if (cb < 16) {
        int ks = cb >> 3, mt = cb & 7;
        gll16(xf + (size_t)(t0 + mt * 16 + l15) * 512 + kk + ks * 32 + quad * 8,
              As + cb * 512);
      } else {
        int bi = cb - 16, ks = bi >> 4, nt = bi & 15;
        gll16(Wgt + (size_t)(c0 + nt * 16 + l15) * 512 + kk + ks * 32 + quad * 8,
              Bs + bi * 512);
      }
    }
  };

  f32x4 qg[4];
  #pragma unroll
  for (int i = 0; i < 4; i++) qg[i] = f32x4{0.f, 0.f, 0.f, 0.f};
  f32x4 zacc[4][4];                               // [mt][z]: z = d-offset 0..3
  #pragma unroll
  for (int i = 0; i < 4; i++)
    #pragma unroll
    for (int z = 0; z < 4; z++) zacc[i][z] = f32x4{0.f, 0.f, 0.f, 0.f};

  for (int s = 0; s < 64; s++) {
    stage(s);
    __syncthreads();               // full drain + barrier: tile resident
    #pragma unroll
    for (int ks = 0; ks < 2; ks++) {
      f16x8 a[4];
      #pragma unroll
      for (int mt = 0; mt < 4; mt++)
        a[mt] = *(const f16x8*)(As + (ks * 8 + mhalf * 4 + mt) * 512 + lane * 8);
      #pragma unroll
      for (int z = 0; z < 4; z++) {
        int nt = (z >> 1) * 8 + (z & 1) * 4 + ntA;
        f16x8 b = *(const f16x8*)(Bs + (ks * 16 + nt) * 512 + lane * 8);
        #pragma unroll
        for (int mt = 0; mt < 4; mt++)
          zacc[mt][z] = __builtin_amdgcn_mfma_f32_16x16x32_f16(a[mt], b, zacc[mt][z], 0, 0, 0);
      }
    }
    if ((s & 7) == 7) {
      // epilogue for j-group jp: d = dh*32 + jp*4 + z.  Wave's output e-slice
      // = ntA*16 + l15 (z indexes d via nt>>2 -- v3 layout, qg stays 16 floats).
      int jp = s >> 3;
      float bgv[4];
      #pragma unroll
      for (int z = 0; z < 4; z++)
        bgv[z] = (float)bgs[(jp * 4 + z) * 64 + ntA * 16 + l15];
      const int d0 = jp * 4;       // local within d-half
      #pragma unroll
      for (int mt = 0; mt < 4; mt++) {
        #pragma unroll
        for (int r = 0; r < 4; r++) {
          int row = mhalf * 64 + mt * 16 + quad * 4 + r;
          f16x4 qp = *(const f16x4*)(Qs + row * 32 + d0);  // q[row][d0..d0+3]
          float g0 = fast_gelu(zacc[mt][0][r] + bgv[0]);
          float g1 = fast_gelu(zacc[mt][1][r] + bgv[1]);
          float g2 = fast_gelu(zacc[mt][2][r] + bgv[2]);
          float g3 = fast_gelu(zacc[mt][3][r] + bgv[3]);
          qg[mt][r] += (float)qp.x * g0 + (float)qp.y * g1 +
                       (float)qp.z * g2 + (float)qp.w * g3;
        }
      }
      #pragma unroll
      for (int i = 0; i < 4; i++)
        #pragma unroll
        for (int z = 0; z < 4; z++) zacc[i][z] = f32x4{0.f, 0.f, 0.f, 0.f};
    }
    __syncthreads();               // reads done before next stage overwrites
  }
  // write fp32 d-half partial [dh][B*H][N][D]
  float* outp = qgp + (size_t)dh * TOK * 512 + ((size_t)bh * 1024) * 64;
  const int eb = ntA * 16;
  #pragma unroll
  for (int mt = 0; mt < 4; mt++) {
    #pragma unroll
    for (int r = 0; r < 4; r++) {
      int tok = mhalf * 64 + mt * 16 + quad * 4 + r;
      int n = nseq0 + tok;
      outp[(size_t)n * 64 + eb + l15] = qg[mt][r];
    }
  }
}

// ---------------------------------------------------------------- flash attention
// Block = (b,h,qtile64), 4 waves x 16 q-rows. qg = sum of 2 fp32 d-half
// partials (one-time per block); counted vmcnt(4) + raw barriers.
__global__ __launch_bounds__(256, 2) void attn_k(
    const float* __restrict__ qgp, const u16* __restrict__ kb,
    const u16* __restrict__ vTb, float* __restrict__ out) {
  __shared__ __align__(16) u16 Ks[2][8 * 512];
  __shared__ __align__(16) u16 Vs[2][8 * 512];
  __shared__ __align__(16) f16 Ps[4][16 * 72];    // per-wave P, row stride 72
  const int idx = blockIdx.x;
  const int bh = idx & 31;   // b*8+h -> XCD = bh%8
  const int qt = idx >> 5;
  const int b_ = bh >> 3, h = bh & 7;
  const int tid = threadIdx.x;
  const int w = tid >> 6, lane = tid & 63, l15 = lane & 15, quad = lane >> 4;

  const float* qg0 = qgp + ((size_t)bh * 1024) * 64;
  const float* qg1 = qg0 + (size_t)TOK * 512;     // partial stride = 2M elems
  const u16* kB  = kb  + (size_t)bh * 1024 * 64;
  const u16* vB  = vTb + (size_t)bh * 64 * 1024;

  f16x8 aq[2];
  #pragma unroll
  for (int ks = 0; ks < 2; ks++) {
    size_t off = (size_t)(qt * 64 + w * 16 + l15) * 64 + ks * 32 + quad * 8;
    f16x8 v;
    #pragma unroll
    for (int e = 0; e < 8; e++)
      v[e] = (f16)(qg0[off + e] + qg1[off + e]);
    aq[ks] = v;
  }

  f32x4 o[4];
  #pragma unroll
  for (int i = 0; i < 4; i++) o[i] = f32x4{0.f, 0.f, 0.f, 0.f};
  float m_old[4], l_old[4];
  #pragma unroll
  for (int r = 0; r < 4; r++) { m_old[r] = -1e30f; l_old[r] = 0.f; }

  auto stageKV = [&](int d, int kt) {
    #pragma unroll
    for (int i = 0; i < 2; i++) {
      int cb = w * 2 + i;
      int ks = cb >> 2, nt = cb & 3;
      gll16(kB + (size_t)(kt * 64 + nt * 16 + l15) * 64 + ks * 32 + quad * 8, Ks[d] + cb * 512);
      gll16(vB + (size_t)(nt * 16 + l15) * 1024 + kt * 64 + ks * 32 + quad * 8, Vs[d] + cb * 512);
    }
  };

  stageKV(0, 0);                   // 4 loads/wave in flight
  int cur = 0;
  for (int kt = 0; kt < 16; kt++) {
    if (kt < 15) { stageKV(cur ^ 1, kt + 1); WAITV(4); }
    else         { WAITV(0); }
    barrier_raw();
    f32x4 s[4];
    #pragma unroll
    for (int nt = 0; nt < 4; nt++) s[nt] = f32x4{0.f, 0.f, 0.f, 0.f};
    #pragma unroll
    for (int ks = 0; ks < 2; ks++)
      #pragma unroll
      for (int nt = 0; nt < 4; nt++) {
        f16x8 kf = *(const f16x8*)(Ks[cur] + (ks * 4 + nt) * 512 + lane * 8);
        s[nt] = __builtin_amdgcn_mfma_f32_16x16x32_f16(aq[ks], kf, s[nt], 0, 0, 0);
      }
    float rmax[4];
    #pragma unroll
    for (int r = 0; r < 4; r++)
      rmax[r] = fmaxf(fmaxf(s[0][r], s[1][r]), fmaxf(s[2][r], s[3][r]));
    #pragma unroll
    for (int off = 1; off < 16; off <<= 1)
      #pragma unroll
      for (int r = 0; r < 4; r++)
        rmax[r] = fmaxf(rmax[r], __shfl_xor(rmax[r], off));
    float alpha[4], rsum[4];
    #pragma unroll
    for (int r = 0; r < 4; r++) {
      float mn = fmaxf(m_old[r], rmax[r]);
      alpha[r] = __expf(m_old[r] - mn);
      m_old[r] = mn;
      rsum[r] = 0.f;
    }
    #pragma unroll
    for (int nt = 0; nt < 4; nt++)
      #pragma unroll
      for (int r = 0; r < 4; r++) {
        float p = __expf(s[nt][r] - m_old[r]);
        rsum[r] += p;
        Ps[w][(quad * 4 + r) * 72 + nt * 16 + l15] = (f16)p;
      }
    #pragma unroll
    for (int off = 1; off < 16; off <<= 1)
      #pragma unroll
      for (int r = 0; r < 4; r++)
        rsum[r] += __shfl_xor(rsum[r], off);
    #pragma unroll
    for (int r = 0; r < 4; r++) l_old[r] = l_old[r] * alpha[r] + rsum[r];
    #pragma unroll
    for (int nt = 0; nt < 4; nt++)
      #pragma unroll
      for (int r = 0; r < 4; r++) o[nt][r] *= alpha[r];
    #pragma unroll
    for (int ks = 0; ks < 2; ks++) {
      f16x8 pa = *(const f16x8*)(&Ps[w][l15 * 72 + ks * 32 + quad * 8]);
      #pragma unroll
      for (int nt = 0; nt < 4; nt++) {
        f16x8 vf = *(const f16x8*)(Vs[cur] + (ks * 4 + nt) * 512 + lane * 8);
        o[nt] = __builtin_amdgcn_mfma_f32_16x16x32_f16(pa, vf, o[nt], 0, 0, 0);
      }
    }
    barrier_raw();                 // protect Ks/Vs[cur] before next stageKV
    cur ^= 1;
  }
  #pragma unroll
  for (int r = 0; r < 4; r++) {
    float inv = 1.f / l_old[r];
    int n = qt * 64 + w * 16 + quad * 4 + r;
    #pragma unroll
    for (int nt = 0; nt < 4; nt++)
      out[((size_t)(b_ * 1024 + n)) * 512 + h * 64 + nt * 16 + l15] = o[nt][r] * inv;
  }
}

// ----------------------------------------------------------------------- host
extern "C" void kernel_launch(void* const* d_in, const int* in_sizes, int n_in,
                              void* d_out, int out_size, void* d_ws, size_t ws_size,
                              hipStream_t stream) {
  const float* x  = (const float*)d_in[0];
  const float* Wq = (const float*)d_in[1];
  const float* bq = (const float*)d_in[2];
  const float* Wk = (const float*)d_in[3];
  const float* bk = (const float*)d_in[4];
  const float* Wv = (const float*)d_in[5];
  const float* bv = (const float*)d_in[6];
  const float* Wg = (const float*)d_in[7];
  const float* bg = (const float*)d_in[8];
  float* out = (float*)d_out;

  const size_t NX = (size_t)TOK * EDIM;        // 2M elems
  const size_t NWG = (size_t)GCOLS * EDIM;     // 16.8M elems
  const size_t NW = (size_t)EDIM * EDIM;       // 256K elems

  char* p = (char*)d_ws;
  u16* xf  = (u16*)p; p += NX * 2;             // x fp16
  u16* Wgt = (u16*)p; p += NWG * 2;            // Wg^T fp16 (33.5 MB)
  u16* Wqt = (u16*)p; p += NW * 2;
  u16* Wkt = (u16*)p; p += NW * 2;
  u16* Wvt = (u16*)p; p += NW * 2;
  u16* qh  = (u16*)p; p += NX * 2;             // q fp16 [B][H][N][D]
  u16* kf  = (u16*)p; p += NX * 2;             // k fp16
  u16* vT  = (u16*)p; p += NX * 2;             // v^T fp16
  float* qgp = (float*)p; p += NX * 4 * 2;     // qg fp32 partials [2][B*H][N][D] (16MB)
  u16* bgh = (u16*)p; p += GCOLS * 2;          // bg fp16 (64KB)

  hipLaunchKernelGGL(cast_f16_k, dim3(NX / 1024), dim3(256), 0, stream,
                     x, xf, (int)NX);
  hipLaunchKernelGGL(cast_f16_k, dim3(GCOLS / 1024), dim3(256), 0, stream,
                     bg, bgh, GCOLS);
  hipLaunchKernelGGL(transpose_f16_k, dim3(EDIM / 32, EDIM / 32), dim3(32, 8), 0, stream,
                     Wq, Wqt, EDIM, EDIM);
  hipLaunchKernelGGL(transpose_f16_k, dim3(EDIM / 32, EDIM / 32), dim3(32, 8), 0, stream,
                     Wk, Wkt, EDIM, EDIM);
  hipLaunchKernelGGL(transpose_f16_k, dim3(EDIM / 32, EDIM / 32), dim3(32, 8), 0, stream,
                     Wv, Wvt, EDIM, EDIM);
  hipLaunchKernelGGL(transpose_f16_k, dim3(GCOLS / 32, EDIM / 32), dim3(32, 8), 0, stream,
                     Wg, Wgt, EDIM, GCOLS);
  hipLaunchKernelGGL(qkv_gemm_k, dim3(TOK / 128, EDIM / 128, 3), dim3(256), 0, stream,
                     xf, Wqt, Wkt, Wvt, bq, bk, bv, qh, kf, vT);
  hipLaunchKernelGGL(qg_fused_k, dim3(512), dim3(512), 0, stream,
                     xf, Wgt, bgh, qh, qgp);
  hipLaunchKernelGGL(attn_k, dim3(512), dim3(256), 0, stream,
                     qgp, kf, vT, out);
}

// Round 10
// 480.443 us; speedup vs baseline: 1.2856x; 1.0555x over previous
//
#include <hip/hip_runtime.h>
#include <math.h>

// Problem constants
#define TOK   4096    // B*N
#define EDIM  512
#define HEADS 8
#define DHEAD 64
#define GCOLS 32768   // H*D*D

typedef unsigned short u16;
typedef _Float16 f16;
typedef __attribute__((ext_vector_type(8))) f16 f16x8;      // 8 fp16 = 4 VGPRs (MFMA A/B frag)
typedef __attribute__((ext_vector_type(4))) f16 f16x4;
typedef __attribute__((ext_vector_type(4))) float f32x4;    // MFMA C/D frag
typedef __attribute__((ext_vector_type(4))) unsigned short u16x4;

typedef const __attribute__((address_space(1))) void* gas_ptr;
typedef __attribute__((address_space(3))) void* las_ptr;

__device__ __forceinline__ void gll16(const void* g, void* lds) {
  // async global->LDS, 16B/lane: per-lane global addr, wave-uniform LDS base,
  // lane i lands at lds + i*16
  __builtin_amdgcn_global_load_lds((gas_ptr)g, (las_ptr)lds, 16, 0, 0);
}

// Counted vmem wait: lets prefetch loads stay in flight across barriers.
#define WAITV(N) asm volatile("s_waitcnt vmcnt(" #N ")" ::: "memory")
// Raw barrier WITHOUT the implicit vmcnt(0) drain __syncthreads emits.
__device__ __forceinline__ void barrier_raw() { asm volatile("s_barrier" ::: "memory"); }

__device__ __forceinline__ u16 f2h_bits(float f) {
  union { f16 h; u16 u; } v; v.h = (f16)f;   // RNE
  return v.u;
}

// Abramowitz-Stegun 7.1.26 erf: |abs err| <= 1.5e-7, ~14 VALU insts.
__device__ __forceinline__ float fast_gelu(float x) {
  float s = x * 0.7071067811865475f;
  float ax = fabsf(s);
  float t = __builtin_amdgcn_rcpf(1.0f + 0.3275911f * ax);
  float poly = t * (0.254829592f + t * (-0.284496736f + t * (1.421413741f +
               t * (-1.453152027f + t * 1.061405429f))));
  float e = __expf(-ax * ax);
  float r = 1.0f - poly * e;
  float erfv = copysignf(r, s);
  return 0.5f * x * (1.0f + erfv);
}

// ---------------------------------------------------------------- cast x -> fp16
__global__ void cast_f16_k(const float* __restrict__ in, u16* __restrict__ out, int n) {
  int i = (blockIdx.x * blockDim.x + threadIdx.x) * 4;
  if (i + 3 < n) {
    float4 f = *(const float4*)(in + i);
    u16x4 h;
    h.x = f2h_bits(f.x); h.y = f2h_bits(f.y);
    h.z = f2h_bits(f.z); h.w = f2h_bits(f.w);
    *(u16x4*)(out + i) = h;
  }
}

// -------------------- transpose W[K][N] -> Wt[N][K] fp16
__global__ void transpose_f16_k(const float* __restrict__ in, u16* __restrict__ out,
                                int K, int N) {
  __shared__ float tile[32][33];
  int n0 = blockIdx.x * 32, k0 = blockIdx.y * 32;
  int tx = threadIdx.x, ty = threadIdx.y;  // (32,8)
  #pragma unroll
  for (int i = 0; i < 4; i++)
    tile[ty + i * 8][tx] = in[(size_t)(k0 + ty + i * 8) * N + n0 + tx];
  __syncthreads();
  #pragma unroll
  for (int i = 0; i < 4; i++)
    out[(size_t)(n0 + ty + i * 8) * K + k0 + tx] = f2h_bits(tile[tx][ty + i * 8]);
}

// ---------------------------------------------------------------- QKV GEMM
// 128x128 tile, BK=64, 4 waves (each 64x64), fp16 MFMA.
// v10: v3 counted-vmcnt schedule + HOISTED ADDRESSING: all 8 per-wave global
// base pointers are loop-invariant (computed once); the only per-stage delta
// is kt*128 B, folded into the global_load_lds offset immediate by the
// compiler (kt fully unrolled). Double-buffer parity is compile-time (kt&1).
__global__ __launch_bounds__(256, 2) void qkv_gemm_k(
    const u16* __restrict__ xf, const u16* __restrict__ Wqt,
    const u16* __restrict__ Wkt, const u16* __restrict__ Wvt,
    const float* __restrict__ bq, const float* __restrict__ bk, const float* __restrict__ bv,
    u16* __restrict__ qho, u16* __restrict__ ko, u16* __restrict__ vTo) {
  __shared__ __align__(16) u16 As[2][16 * 512];   // 2 x 16KB
  __shared__ __align__(16) u16 Bs[2][16 * 512];   // 2 x 16KB  -> 64KB, 2 blk/CU
  const int which = blockIdx.z;
  const u16* Wt = which == 0 ? Wqt : (which == 1 ? Wkt : Wvt);
  const float* bias = which == 0 ? bq : (which == 1 ? bk : bv);
  const int m0 = blockIdx.x * 128;
  const int n0 = blockIdx.y * 128;
  const int tid = threadIdx.x;
  const int w = tid >> 6, lane = tid & 63, l15 = lane & 15, quad = lane >> 4;
  const int mhalf = w >> 1, nhalf = w & 1;

  // Hoisted per-wave bases: waves 0-1 own the 16 A blocks, waves 2-3 the 16 B.
  // g8[i]/l8[i] indexed only by compile-time i (rule #20 safe).
  const u16* g8[8];
  u16* l8[8];
  #pragma unroll
  for (int i = 0; i < 8; i++) {
    int cb = w * 8 + i;
    if (w < 2) {
      int ks = cb >> 3, mt = cb & 7;
      g8[i] = xf + (size_t)(m0 + mt * 16 + l15) * 512 + ks * 32 + quad * 8;
      l8[i] = As[0] + cb * 512;
    } else {
      int bi = cb - 16, ks = bi >> 3, nt = bi & 7;
      g8[i] = Wt + (size_t)(n0 + nt * 16 + l15) * 512 + ks * 32 + quad * 8;
      l8[i] = Bs[0] + bi * 512;
    }
  }
  // dbuf stride: As[1]-As[0] == Bs[1]-Bs[0] == 8192 elems

  f32x4 acc[4][4];
  #pragma unroll
  for (int i = 0; i < 4; i++)
    #pragma unroll
    for (int j = 0; j < 4; j++) acc[i][j] = f32x4{0.f, 0.f, 0.f, 0.f};

  // initial stage kt=0 -> buf 0 (offset 0)
  #pragma unroll
  for (int i = 0; i < 8; i++) gll16(g8[i], l8[i]);

  #pragma unroll
  for (int kt = 0; kt < 8; kt++) {
    const int buf = kt & 1;                     // compile-time
    if (kt < 7) {
      const int nb = (kt + 1) & 1;
      #pragma unroll
      for (int i = 0; i < 8; i++)
        gll16(g8[i] + (kt + 1) * 64, l8[i] + nb * 8192);   // offset folds to imm
      WAITV(8);
    } else {
      WAITV(0);
    }
    barrier_raw();                 // all waves' stage-kt data resident
    const u16* Asb = As[buf];
    const u16* Bsb = Bs[buf];
    #pragma unroll
    for (int ks = 0; ks < 2; ks++) {
      f16x8 a[4], b[4];
      #pragma unroll
      for (int mt = 0; mt < 4; mt++)
        a[mt] = *(const f16x8*)(Asb + (ks * 8 + mhalf * 4 + mt) * 512 + lane * 8);
      #pragma unroll
      for (int nt = 0; nt < 4; nt++)
        b[nt] = *(const f16x8*)(Bsb + (ks * 8 + nhalf * 4 + nt) * 512 + lane * 8);
      #pragma unroll
      for (int mt = 0; mt < 4; mt++)
        #pragma unroll
        for (int nt = 0; nt < 4; nt++)
          acc[mt][nt] = __builtin_amdgcn_mfma_f32_16x16x32_f16(a[mt], b[nt], acc[mt][nt], 0, 0, 0);
    }
    barrier_raw();                 // protect buf before next iter's stage()
  }
  #pragma unroll
  for (int nt = 0; nt < 4; nt++) {
    int col = n0 + (nhalf * 4 + nt) * 16 + l15;
    float bia = bias[col];
    int h = col >> 6, d = col & 63;
    #pragma unroll
    for (int mt = 0; mt < 4; mt++) {
      #pragma unroll
      for (int r = 0; r < 4; r++) {
        int t = m0 + (mhalf * 4 + mt) * 16 + quad * 4 + r;
        int b_ = t >> 10, n = t & 1023;
        float val = acc[mt][nt][r] + bia;
        size_t idx = (((size_t)(b_ * 8 + h) * 1024) + n) * 64 + d;
        if (which == 0)      qho[idx] = f2h_bits(val);
        else if (which == 1) ko[idx] = f2h_bits(val);
        else                 vTo[(((size_t)(b_ * 8 + h) * 64) + d) * 1024 + n] = f2h_bits(val);
      }
    }
  }
}

// ---------------------------------------------------------------- fused g-GEMM + q.g
// v10 = R2's v3 (best measured: 128 tok x head x full d, 16 jp x 8 kk = 128
// stages, dbuf As/Bs, issue-before-WAITV(6), two raw barriers, 1 blk/CU,
// fp16 qg16 direct output) + HOISTED ADDRESSING:
//  - A jobs (2/wave) have fully loop-invariant bases; per-stage delta kk*128 B
//    folds into the load's offset immediate (kk unrolled).
//  - B jobs (4/wave) advance by a constant 256*512 elems once per jp.
//  - dbuf parity is compile-time: stages/jp = 8 (even) => buf = kk&1.
// Schedule/layout/counts byte-identical to R2; only address VALU removed.
__global__ __launch_bounds__(512, 2) void qg_fused_k(
    const u16* __restrict__ xf, const u16* __restrict__ Wgt,
    const float* __restrict__ bg, const u16* __restrict__ qh,
    u16* __restrict__ qg16) {
  __shared__ __align__(16) u16 As[2][16 * 512];   // 2 x 16KB: 128 tok x 64 K
  __shared__ __align__(16) u16 Bs[2][32 * 512];   // 2 x 32KB: 256 cols x 64 K
  __shared__ __align__(16) u16 Qs[128 * 64];      // 16KB: q fp16 rows
  __shared__ __align__(16) float bgs[4096];       // 16KB: bg head slice
  const int head = blockIdx.x & 7;                // XCD-pinned per head
  const int t0 = (blockIdx.x >> 3) * 128;
  const int tid = threadIdx.x;
  const int w = tid >> 6, lane = tid & 63, l15 = lane & 15, quad = lane >> 4;
  const int mhalf = w >> 2;   // 0..1  (token half)
  const int ntA = w & 3;      // 0..3  (e-range /16)
  const int b_ = t0 >> 10, nseq0 = t0 & 1023;
  const u16* qbase = qh + (((size_t)(b_ * 8 + head) * 1024) + nseq0) * 64;
  const float* bgbase = bg + head * 4096;

  // prologue: Qs (16KB fp16) + bgs (16KB f32); drained by the first WAITV(6)
  #pragma unroll
  for (int i = 0; i < 2; i++) {
    int cb = w * 2 + i;
    gll16(qbase + (size_t)cb * 512 + (size_t)lane * 8, Qs + (size_t)cb * 512);
    gll16(bgbase + (size_t)cb * 256 + (size_t)lane * 4, bgs + (size_t)cb * 256);
  }

  // Hoisted bases: A = 16 blocks, 2/wave (i=0,1); B = 32 blocks, 4/wave.
  const u16* gA[2];
  u16* lA[2];
  #pragma unroll
  for (int i = 0; i < 2; i++) {
    int cb = w * 2 + i, ks = cb >> 3, mt = cb & 7;
    gA[i] = xf + (size_t)(t0 + mt * 16 + l15) * 512 + ks * 32 + quad * 8;
    lA[i] = As[0] + cb * 512;
  }
  const u16* gB[4];
  u16* lB[4];
  #pragma unroll
  for (int i = 0; i < 4; i++) {
    int bi = w * 4 + i, ks = bi >> 4, nt = bi & 15;
    gB[i] = Wgt + (size_t)(head * 4096 + nt * 16 + l15) * 512 + ks * 32 + quad * 8;
    lB[i] = Bs[0] + bi * 512;
  }
  // dbuf strides: As 8192 elems, Bs 16384 elems. B jp stride: 256*512 elems.

  f32x4 qg[4];
  #pragma unroll
  for (int i = 0; i < 4; i++) qg[i] = f32x4{0.f, 0.f, 0.f, 0.f};
  f32x4 zacc[4][4];                               // [mt][z]: z = d-offset 0..3
  #pragma unroll
  for (int i = 0; i < 4; i++)
    #pragma unroll
    for (int z = 0; z < 4; z++) zacc[i][z] = f32x4{0.f, 0.f, 0.f, 0.f};

  // initial stage (jp=0, kk=0) -> buf 0
  #pragma unroll
  for (int i = 0; i < 2; i++) gll16(gA[i], lA[i]);
  #pragma unroll
  for (int i = 0; i < 4; i++) gll16(gB[i], lB[i]);

  for (int jp = 0; jp < 16; jp++) {
    #pragma unroll
    for (int kk = 0; kk < 8; kk++) {
      const int buf = kk & 1;                     // compile-time (8 stages/jp, even)
      // prefetch stage s+1 into buf^1; all offsets compile-time constants
      if (jp < 15 || kk < 7) {
        const int nb = (kk + 1) & 1;
        if (kk == 7) {
          // next jp, kk=0: advance B bases by one 256-col panel
          #pragma unroll
          for (int i = 0; i < 4; i++) gB[i] += 256 * 512;
          #pragma unroll
          for (int i = 0; i < 2; i++) gll16(gA[i], lA[i] + nb * 8192);
          #pragma unroll
          for (int i = 0; i < 4; i++) gll16(gB[i], lB[i] + nb * 16384);
        } else {
          #pragma unroll
          for (int i = 0; i < 2; i++) gll16(gA[i] + (kk + 1) * 64, lA[i] + nb * 8192);
          #pragma unroll
          for (int i = 0; i < 4; i++) gll16(gB[i] + (kk + 1) * 64, lB[i] + nb * 16384);
        }
        WAITV(6);                  // stage-s resident; prefetch stays in flight
      } else {
        WAITV(0);                  // final stage
      }
      barrier_raw();
      const u16* Asb = As[buf];
      const u16* Bsb = Bs[buf];
      #pragma unroll
      for (int ks = 0; ks < 2; ks++) {
        f16x8 a[4];
        #pragma unroll
        for (int mt = 0; mt < 4; mt++)
          a[mt] = *(const f16x8*)(Asb + (ks * 8 + mhalf * 4 + mt) * 512 + lane * 8);
        #pragma unroll
        for (int z = 0; z < 4; z++) {
          int nt = (z >> 1) * 8 + (z & 1) * 4 + ntA;
          f16x8 b = *(const f16x8*)(Bsb + (ks * 16 + nt) * 512 + lane * 8);
          #pragma unroll
          for (int mt = 0; mt < 4; mt++)
            zacc[mt][z] = __builtin_amdgcn_mfma_f32_16x16x32_f16(a[mt], b, zacc[mt][z], 0, 0, 0);
        }
      }
      if (kk == 7) {
        // epilogue for j-pair jp: bias (LDS) + gelu + contract with fp16 q.
        // Runs while the next stage's loads are in flight.
        float bgv[4];
        #pragma unroll
        for (int z = 0; z < 4; z++) {
          int nt = (z >> 1) * 8 + (z & 1) * 4 + ntA;
          bgv[z] = bgs[jp * 256 + nt * 16 + l15];
        }
        const int d0 = 4 * jp;
        #pragma unroll
        for (int mt = 0; mt < 4; mt++) {
          #pragma unroll
          for (int r = 0; r < 4; r++) {
            int row = mhalf * 64 + mt * 16 + quad * 4 + r;
            f16x4 qp = *(const f16x4*)(Qs + row * 64 + d0);  // q[row][d0..d0+3]
            float g0 = fast_gelu(zacc[mt][0][r] + bgv[0]);
            float g1 = fast_gelu(zacc[mt][1][r] + bgv[1]);
            float g2 = fast_gelu(zacc[mt][2][r] + bgv[2]);
            float g3 = fast_gelu(zacc[mt][3][r] + bgv[3]);
            qg[mt][r] += (float)qp.x * g0 + (float)qp.y * g1 +
                         (float)qp.z * g2 + (float)qp.w * g3;
          }
        }
        #pragma unroll
        for (int i = 0; i < 4; i++)
          #pragma unroll
          for (int z = 0; z < 4; z++) zacc[i][z] = f32x4{0.f, 0.f, 0.f, 0.f};
      }
      barrier_raw();               // protect buf before next iter's stage()
    }
  }
  // write complete qg as fp16 [B][H][N][D]
  const int eb = ntA * 16;
  #pragma unroll
  for (int mt = 0; mt < 4; mt++) {
    #pragma unroll
    for (int r = 0; r < 4; r++) {
      int t = t0 + mhalf * 64 + mt * 16 + quad * 4 + r;
      int bb = t >> 10, n = t & 1023;
      qg16[(((size_t)(bb * 8 + head) * 1024) + n) * 64 + eb + l15] = f2h_bits(qg[mt][r]);
    }
  }
}

// ---------------------------------------------------------------- flash attention
// Block = (b,h,qtile64), 4 waves x 16 q-rows. qg read directly as fp16;
// K/V double-buffered, counted vmcnt(4) + raw barriers (R2 version).
__global__ __launch_bounds__(256, 2) void attn_k(
    const u16* __restrict__ qg16, const u16* __restrict__ kb,
    const u16* __restrict__ vTb, float* __restrict__ out) {
  __shared__ __align__(16) u16 Ks[2][8 * 512];
  __shared__ __align__(16) u16 Vs[2][8 * 512];
  __shared__ __align__(16) f16 Ps[4][16 * 72];    // per-wave P, row stride 72
  const int idx = blockIdx.x;
  const int bh = idx & 31;   // b*8+h -> XCD = bh%8
  const int qt = idx >> 5;
  const int b_ = bh >> 3, h = bh & 7;
  const int tid = threadIdx.x;
  const int w = tid >> 6, lane = tid & 63, l15 = lane & 15, quad = lane >> 4;

  const u16* qgB = qg16 + (size_t)bh * 1024 * 64;
  const u16* kB  = kb  + (size_t)bh * 1024 * 64;
  const u16* vB  = vTb + (size_t)bh * 64 * 1024;

  f16x8 aq[2];
  #pragma unroll
  for (int ks = 0; ks < 2; ks++)
    aq[ks] = *(const f16x8*)(qgB + (size_t)(qt * 64 + w * 16 + l15) * 64 + ks * 32 + quad * 8);

  f32x4 o[4];
  #pragma unroll
  for (int i = 0; i < 4; i++) o[i] = f32x4{0.f, 0.f, 0.f, 0.f};
  float m_old[4], l_old[4];
  #pragma unroll
  for (int r = 0; r < 4; r++) { m_old[r] = -1e30f; l_old[r] = 0.f; }

  auto stageKV = [&](int d, int kt) {
    #pragma unroll
    for (int i = 0; i < 2; i++) {
      int cb = w * 2 + i;
      int ks = cb >> 2, nt = cb & 3;
      gll16(kB + (size_t)(kt * 64 + nt * 16 + l15) * 64 + ks * 32 + quad * 8, Ks[d] + cb * 512);
      gll16(vB + (size_t)(nt * 16 + l15) * 1024 + kt * 64 + ks * 32 + quad * 8, Vs[d] + cb * 512);
    }
  };

  stageKV(0, 0);                   // 4 loads/wave in flight
  int cur = 0;
  for (int kt = 0; kt < 16; kt++) {
    if (kt < 15) { stageKV(cur ^ 1, kt + 1); WAITV(4); }
    else         { WAITV(0); }
    barrier_raw();
    f32x4 s[4];
    #pragma unroll
    for (int nt = 0; nt < 4; nt++) s[nt] = f32x4{0.f, 0.f, 0.f, 0.f};
    #pragma unroll
    for (int ks = 0; ks < 2; ks++)
      #pragma unroll
      for (int nt = 0; nt < 4; nt++) {
        f16x8 kf = *(const f16x8*)(Ks[cur] + (ks * 4 + nt) * 512 + lane * 8);
        s[nt] = __builtin_amdgcn_mfma_f32_16x16x32_f16(aq[ks], kf, s[nt], 0, 0, 0);
      }
    float rmax[4];
    #pragma unroll
    for (int r = 0; r < 4; r++)
      rmax[r] = fmaxf(fmaxf(s[0][r], s[1][r]), fmaxf(s[2][r], s[3][r]));
    #pragma unroll
    for (int off = 1; off < 16; off <<= 1)
      #pragma unroll
      for (int r = 0; r < 4; r++)
        rmax[r] = fmaxf(rmax[r], __shfl_xor(rmax[r], off));
    float alpha[4], rsum[4];
    #pragma unroll
    for (int r = 0; r < 4; r++) {
      float mn = fmaxf(m_old[r], rmax[r]);
      alpha[r] = __expf(m_old[r] - mn);
      m_old[r] = mn;
      rsum[r] = 0.f;
    }
    #pragma unroll
    for (int nt = 0; nt < 4; nt++)
      #pragma unroll
      for (int r = 0; r < 4; r++) {
        float p = __expf(s[nt][r] - m_old[r]);
        rsum[r] += p;
        Ps[w][(quad * 4 + r) * 72 + nt * 16 + l15] = (f16)p;
      }
    #pragma unroll
    for (int off = 1; off < 16; off <<= 1)
      #pragma unroll
      for (int r = 0; r < 4; r++)
        rsum[r] += __shfl_xor(rsum[r], off);
    #pragma unroll
    for (int r = 0; r < 4; r++) l_old[r] = l_old[r] * alpha[r] + rsum[r];
    #pragma unroll
    for (int nt = 0; nt < 4; nt++)
      #pragma unroll
      for (int r = 0; r < 4; r++) o[nt][r] *= alpha[r];
    #pragma unroll
    for (int ks = 0; ks < 2; ks++) {
      f16x8 pa = *(const f16x8*)(&Ps[w][l15 * 72 + ks * 32 + quad * 8]);
      #pragma unroll
      for (int nt = 0; nt < 4; nt++) {
        f16x8 vf = *(const f16x8*)(Vs[cur] + (ks * 4 + nt) * 512 + lane * 8);
        o[nt] = __builtin_amdgcn_mfma_f32_16x16x32_f16(pa, vf, o[nt], 0, 0, 0);
      }
    }
    barrier_raw();                 // protect Ks/Vs[cur] before next stageKV
    cur ^= 1;
  }
  #pragma unroll
  for (int r = 0; r < 4; r++) {
    float inv = 1.f / l_old[r];
    int n = qt * 64 + w * 16 + quad * 4 + r;
    #pragma unroll
    for (int nt = 0; nt < 4; nt++)
      out[((size_t)(b_ * 1024 + n)) * 512 + h * 64 + nt * 16 + l15] = o[nt][r] * inv;
  }
}

// ----------------------------------------------------------------------- host
extern "C" void kernel_launch(void* const* d_in, const int* in_sizes, int n_in,
                              void* d_out, int out_size, void* d_ws, size_t ws_size,
                              hipStream_t stream) {
  const float* x  = (const float*)d_in[0];
  const float* Wq = (const float*)d_in[1];
  const float* bq = (const float*)d_in[2];
  const float* Wk = (const float*)d_in[3];
  const float* bk = (const float*)d_in[4];
  const float* Wv = (const float*)d_in[5];
  const float* bv = (const float*)d_in[6];
  const float* Wg = (const float*)d_in[7];
  const float* bg = (const float*)d_in[8];
  float* out = (float*)d_out;

  const size_t NX = (size_t)TOK * EDIM;        // 2M elems
  const size_t NWG = (size_t)GCOLS * EDIM;     // 16.8M elems
  const size_t NW = (size_t)EDIM * EDIM;       // 256K elems

  char* p = (char*)d_ws;
  u16* xf  = (u16*)p; p += NX * 2;             // x fp16
  u16* Wgt = (u16*)p; p += NWG * 2;            // Wg^T fp16 (33.5 MB)
  u16* Wqt = (u16*)p; p += NW * 2;
  u16* Wkt = (u16*)p; p += NW * 2;
  u16* Wvt = (u16*)p; p += NW * 2;
  u16* qh  = (u16*)p; p += NX * 2;             // q fp16 [B][H][N][D]
  u16* kf  = (u16*)p; p += NX * 2;             // k fp16
  u16* vT  = (u16*)p; p += NX * 2;             // v^T fp16
  u16* qg16 = (u16*)p; p += NX * 2;            // qg fp16 [B][H][N][D] (complete)

  hipLaunchKernelGGL(cast_f16_k, dim3(NX / 1024), dim3(256), 0, stream,
                     x, xf, (int)NX);
  hipLaunchKernelGGL(transpose_f16_k, dim3(EDIM / 32, EDIM / 32), dim3(32, 8), 0, stream,
                     Wq, Wqt, EDIM, EDIM);
  hipLaunchKernelGGL(transpose_f16_k, dim3(EDIM / 32, EDIM / 32), dim3(32, 8), 0, stream,
                     Wk, Wkt, EDIM, EDIM);
  hipLaunchKernelGGL(transpose_f16_k, dim3(EDIM / 32, EDIM / 32), dim3(32, 8), 0, stream,
                     Wv, Wvt, EDIM, EDIM);
  hipLaunchKernelGGL(transpose_f16_k, dim3(GCOLS / 32, EDIM / 32), dim3(32, 8), 0, stream,
                     Wg, Wgt, EDIM, GCOLS);
  hipLaunchKernelGGL(qkv_gemm_k, dim3(TOK / 128, EDIM / 128, 3), dim3(256), 0, stream,
                     xf, Wqt, Wkt, Wvt, bq, bk, bv, qh, kf, vT);
  hipLaunchKernelGGL(qg_fused_k, dim3(256), dim3(512), 0, stream,
                     xf, Wgt, bg, qh, qg16);
  hipLaunchKernelGGL(attn_k, dim3(512), dim3(256), 0, stream,
                     qg16, kf, vT, out);
}

// Round 11
// 425.547 us; speedup vs baseline: 1.4515x; 1.1290x over previous
//
#include <hip/hip_runtime.h>
#include <math.h>

// Problem constants
#define TOK   4096    // B*N
#define EDIM  512
#define HEADS 8
#define DHEAD 64
#define GCOLS 32768   // H*D*D

typedef unsigned short u16;
typedef _Float16 f16;
typedef __attribute__((ext_vector_type(8))) f16 f16x8;      // 8 fp16 = 4 VGPRs (MFMA A/B frag)
typedef __attribute__((ext_vector_type(4))) f16 f16x4;
typedef __attribute__((ext_vector_type(4))) float f32x4;    // MFMA C/D frag
typedef __attribute__((ext_vector_type(4))) unsigned short u16x4;
typedef __attribute__((ext_vector_type(8))) unsigned short u16x8;

typedef const __attribute__((address_space(1))) void* gas_ptr;
typedef __attribute__((address_space(3))) void* las_ptr;

__device__ __forceinline__ void gll16(const void* g, void* lds) {
  // async global->LDS, 16B/lane: per-lane global addr, wave-uniform LDS base,
  // lane i lands at lds + i*16
  __builtin_amdgcn_global_load_lds((gas_ptr)g, (las_ptr)lds, 16, 0, 0);
}

// Counted vmem wait: lets prefetch loads stay in flight across barriers.
#define WAITV(N) asm volatile("s_waitcnt vmcnt(" #N ")" ::: "memory")
// Raw barrier WITHOUT the implicit vmcnt(0) drain __syncthreads emits.
__device__ __forceinline__ void barrier_raw() { asm volatile("s_barrier" ::: "memory"); }

__device__ __forceinline__ u16 f2h_bits(float f) {
  union { f16 h; u16 u; } v; v.h = (f16)f;   // RNE
  return v.u;
}

// Abramowitz-Stegun 7.1.26 erf: |abs err| <= 1.5e-7, ~14 VALU insts.
__device__ __forceinline__ float fast_gelu(float x) {
  float s = x * 0.7071067811865475f;
  float ax = fabsf(s);
  float t = __builtin_amdgcn_rcpf(1.0f + 0.3275911f * ax);
  float poly = t * (0.254829592f + t * (-0.284496736f + t * (1.421413741f +
               t * (-1.453152027f + t * 1.061405429f))));
  float e = __expf(-ax * ax);
  float r = 1.0f - poly * e;
  float erfv = copysignf(r, s);
  return 0.5f * x * (1.0f + erfv);
}

// ---------------------------------------------------------------- cast x -> fp16
__global__ void cast_f16_k(const float* __restrict__ in, u16* __restrict__ out, int n) {
  int i = (blockIdx.x * blockDim.x + threadIdx.x) * 4;
  if (i + 3 < n) {
    float4 f = *(const float4*)(in + i);
    u16x4 h;
    h.x = f2h_bits(f.x); h.y = f2h_bits(f.y);
    h.z = f2h_bits(f.z); h.w = f2h_bits(f.w);
    *(u16x4*)(out + i) = h;
  }
}

// -------------------- wide transpose W[K][N] -> Wt[N][K] fp16
// 64x64 tile, 256 threads. Loads float4 (16B/lane), stores u16x8 (16B/lane).
// LDS f32 tile padded to 65: bank = (k*65+n)%32 = (k+n)%32 -> conflict-free
// on row writes; column reads hit each bank exactly 2x (free, m136).
// (Replaces the scalar-load/scalar-store 32x32 version -- G13.)
__global__ void transpose_f16_wide_k(const float* __restrict__ in, u16* __restrict__ out,
                                     int K, int N) {
  __shared__ float tile[64][65];
  const int n0 = blockIdx.x * 64, k0 = blockIdx.y * 64;
  const int tid = threadIdx.x;   // 256
  #pragma unroll
  for (int i = 0; i < 4; i++) {
    int c = tid + i * 256;       // 1024 float4 chunks: row c>>4, col4 c&15
    int kr = c >> 4, c4 = (c & 15) * 4;
    float4 f = *(const float4*)(in + (size_t)(k0 + kr) * N + n0 + c4);
    tile[kr][c4 + 0] = f.x;
    tile[kr][c4 + 1] = f.y;
    tile[kr][c4 + 2] = f.z;
    tile[kr][c4 + 3] = f.w;
  }
  __syncthreads();
  #pragma unroll
  for (int i = 0; i < 2; i++) {
    int c = tid + i * 256;       // 512 u16x8 chunks: out-row c>>3, k-chunk c&7
    int nr = c >> 3, kc = (c & 7) * 8;
    u16x8 h;
    #pragma unroll
    for (int e = 0; e < 8; e++)
      h[e] = f2h_bits(tile[kc + e][nr]);
    *(u16x8*)(out + (size_t)(n0 + nr) * K + k0 + kc) = h;
  }
}

// merged z=3 variant for Wq/Wk/Wv (512x512 each): one launch instead of three
__global__ void transpose3_f16_k(const float* __restrict__ Wq, const float* __restrict__ Wk,
                                 const float* __restrict__ Wv, u16* __restrict__ Wqt,
                                 u16* __restrict__ Wkt, u16* __restrict__ Wvt) {
  __shared__ float tile[64][65];
  const int which = blockIdx.z;
  const float* in = which == 0 ? Wq : (which == 1 ? Wk : Wv);
  u16* out = which == 0 ? Wqt : (which == 1 ? Wkt : Wvt);
  const int n0 = blockIdx.x * 64, k0 = blockIdx.y * 64;
  const int tid = threadIdx.x;
  #pragma unroll
  for (int i = 0; i < 4; i++) {
    int c = tid + i * 256;
    int kr = c >> 4, c4 = (c & 15) * 4;
    float4 f = *(const float4*)(in + (size_t)(k0 + kr) * EDIM + n0 + c4);
    tile[kr][c4 + 0] = f.x;
    tile[kr][c4 + 1] = f.y;
    tile[kr][c4 + 2] = f.z;
    tile[kr][c4 + 3] = f.w;
  }
  __syncthreads();
  #pragma unroll
  for (int i = 0; i < 2; i++) {
    int c = tid + i * 256;
    int nr = c >> 3, kc = (c & 7) * 8;
    u16x8 h;
    #pragma unroll
    for (int e = 0; e < 8; e++)
      h[e] = f2h_bits(tile[kc + e][nr]);
    *(u16x8*)(out + (size_t)(n0 + nr) * EDIM + k0 + kc) = h;
  }
}

// ---------------------------------------------------------------- QKV GEMM
// 128x128 tile, BK=64, 4 waves (each 64x64), fp16 MFMA.
// v3 (R2-exact, best measured): double-buffer + prefetch + COUNTED vmcnt(8)
// with raw s_barrier -- prefetch stays in flight across both barriers.
__global__ __launch_bounds__(256, 2) void qkv_gemm_k(
    const u16* __restrict__ xf, const u16* __restrict__ Wqt,
    const u16* __restrict__ Wkt, const u16* __restrict__ Wvt,
    const float* __restrict__ bq, const float* __restrict__ bk, const float* __restrict__ bv,
    u16* __restrict__ qho, u16* __restrict__ ko, u16* __restrict__ vTo) {
  __shared__ __align__(16) u16 As[2][16 * 512];   // 2 x 16KB
  __shared__ __align__(16) u16 Bs[2][16 * 512];   // 2 x 16KB  -> 64KB, 2 blk/CU
  const int which = blockIdx.z;
  const u16* Wt = which == 0 ? Wqt : (which == 1 ? Wkt : Wvt);
  const float* bias = which == 0 ? bq : (which == 1 ? bk : bv);
  const int m0 = blockIdx.x * 128;
  const int n0 = blockIdx.y * 128;
  const int tid = threadIdx.x;
  const int w = tid >> 6, lane = tid & 63, l15 = lane & 15, quad = lane >> 4;
  const int mhalf = w >> 1, nhalf = w & 1;

  f32x4 acc[4][4];
  #pragma unroll
  for (int i = 0; i < 4; i++)
    #pragma unroll
    for (int j = 0; j < 4; j++) acc[i][j] = f32x4{0.f, 0.f, 0.f, 0.f};

  auto stage = [&](int d, int kk) {
    #pragma unroll
    for (int i = 0; i < 8; i++) {
      int cb = w * 8 + i;
      if (cb < 16) {
        int ks = cb >> 3, mt = cb & 7;
        gll16(xf + (size_t)(m0 + mt * 16 + l15) * 512 + kk + ks * 32 + quad * 8,
              As[d] + cb * 512);
      } else {
        int bi = cb - 16, ks = bi >> 3, nt = bi & 7;
        gll16(Wt + (size_t)(n0 + nt * 16 + l15) * 512 + kk + ks * 32 + quad * 8,
              Bs[d] + bi * 512);
      }
    }
  };

  stage(0, 0);                     // 8 loads/wave in flight
  int cur = 0;
  for (int kt = 0; kt < 8; kt++) {
    if (kt < 7) { stage(cur ^ 1, (kt + 1) * 64); WAITV(8); }  // keep prefetch in flight
    else        { WAITV(0); }
    barrier_raw();                 // all waves' stage-kt data resident
    const u16* Asb = As[cur];
    const u16* Bsb = Bs[cur];
    #pragma unroll
    for (int ks = 0; ks < 2; ks++) {
      f16x8 a[4], b[4];
      #pragma unroll
      for (int mt = 0; mt < 4; mt++)
        a[mt] = *(const f16x8*)(Asb + (ks * 8 + mhalf * 4 + mt) * 512 + lane * 8);
      #pragma unroll
      for (int nt = 0; nt < 4; nt++)
        b[nt] = *(const f16x8*)(Bsb + (ks * 8 + nhalf * 4 + nt) * 512 + lane * 8);
      #pragma unroll
      for (int mt = 0; mt < 4; mt++)
        #pragma unroll
        for (int nt = 0; nt < 4; nt++)
          acc[mt][nt] = __builtin_amdgcn_mfma_f32_16x16x32_f16(a[mt], b[nt], acc[mt][nt], 0, 0, 0);
    }
    barrier_raw();                 // protect buf[cur] before next iter's stage()
    cur ^= 1;
  }
  #pragma unroll
  for (int nt = 0; nt < 4; nt++) {
    int col = n0 + (nhalf * 4 + nt) * 16 + l15;
    float bia = bias[col];
    int h = col >> 6, d = col & 63;
    #pragma unroll
    for (int mt = 0; mt < 4; mt++) {
      #pragma unroll
      for (int r = 0; r < 4; r++) {
        int t = m0 + (mhalf * 4 + mt) * 16 + quad * 4 + r;
        int b_ = t >> 10, n = t & 1023;
        float val = acc[mt][nt][r] + bia;
        size_t idx = (((size_t)(b_ * 8 + h) * 1024) + n) * 64 + d;
        if (which == 0)      qho[idx] = f2h_bits(val);
        else if (which == 1) ko[idx] = f2h_bits(val);
        else                 vTo[(((size_t)(b_ * 8 + h) * 64) + d) * 1024 + n] = f2h_bits(val);
      }
    }
  }
}

// ---------------------------------------------------------------- fused g-GEMM + q.g
// v3 (R2-exact, best measured 279us): 128 tok x head x full d, 16 jp x 8 kk
// = 128 stages, dbuf As/Bs, issue-before-WAITV(6), two raw barriers; bg
// staged to LDS so the epilogue issues no global loads; fp16 qg16 output.
// Ten rounds of structural variants (counted-vmcnt depth, triple-buffer,
// tile/occupancy changes, m97-drain at 2-4 blk/CU, hoisted addressing) all
// measured >= this form -- the accumulator footprint pins it to 2 waves/SIMD
// and the schedule is already latency-optimal there.
__global__ __launch_bounds__(512, 2) void qg_fused_k(
    const u16* __restrict__ xf, const u16* __restrict__ Wgt,
    const float* __restrict__ bg, const u16* __restrict__ qh,
    u16* __restrict__ qg16) {
  __shared__ __align__(16) u16 As[2][16 * 512];   // 2 x 16KB: 128 tok x 64 K
  __shared__ __align__(16) u16 Bs[2][32 * 512];   // 2 x 32KB: 256 cols x 64 K
  __shared__ __align__(16) u16 Qs[128 * 64];      // 16KB: q fp16 rows
  __shared__ __align__(16) float bgs[4096];       // 16KB: bg head slice
  const int head = blockIdx.x & 7;                // XCD-pinned per head
  const int t0 = (blockIdx.x >> 3) * 128;
  const int tid = threadIdx.x;
  const int w = tid >> 6, lane = tid & 63, l15 = lane & 15, quad = lane >> 4;
  const int mhalf = w >> 2;   // 0..1  (token half)
  const int ntA = w & 3;      // 0..3  (e-range /16)
  const int b_ = t0 >> 10, nseq0 = t0 & 1023;
  const u16* qbase = qh + (((size_t)(b_ * 8 + head) * 1024) + nseq0) * 64;
  const float* bgbase = bg + head * 4096;

  // stage Qs (16KB fp16) + bgs (16KB f32); drained by the first WAITV(6)
  #pragma unroll
  for (int i = 0; i < 2; i++) {
    int cb = w * 2 + i;
    gll16(qbase + (size_t)cb * 512 + (size_t)lane * 8, Qs + (size_t)cb * 512);
    gll16(bgbase + (size_t)cb * 256 + (size_t)lane * 4, bgs + (size_t)cb * 256);
  }

  auto stage = [&](int d, int s) {
    int jp = s >> 3, kk = (s & 7) << 6;
    int c0 = head * 4096 + jp * 256;              // 256 contiguous cols (4 d's)
    #pragma unroll
    for (int i = 0; i < 6; i++) {
      int cb = w * 6 + i;
      if (cb < 16) {
        int ks = cb >> 3, mt = cb & 7;
        gll16(xf + (size_t)(t0 + mt * 16 + l15) * 512 + kk + ks * 32 + quad * 8,
              As[d] + cb * 512);
      } else {
        int bi = cb - 16, ks = bi >> 4, nt = bi & 15;
        gll16(Wgt + (size_t)(c0 + nt * 16 + l15) * 512 + kk + ks * 32 + quad * 8,
              Bs[d] + bi * 512);
      }
    }
  };

  f32x4 qg[4];
  #pragma unroll
  for (int i = 0; i < 4; i++) qg[i] = f32x4{0.f, 0.f, 0.f, 0.f};
  f32x4 zacc[4][4];                               // [mt][z]: z = d-offset 0..3
  #pragma unroll
  for (int i = 0; i < 4; i++)
    #pragma unroll
    for (int z = 0; z < 4; z++) zacc[i][z] = f32x4{0.f, 0.f, 0.f, 0.f};

  stage(0, 0);                     // 6 loads/wave in flight (+4 prologue)
  int cur = 0;
  for (int s = 0; s < 128; s++) {
    if (s < 127) { stage(cur ^ 1, s + 1); WAITV(6); }  // stage-s done, prefetch flying
    else         { WAITV(0); }
    barrier_raw();                 // all waves' stage-s data resident
    const u16* Asb = As[cur];
    const u16* Bsb = Bs[cur];
    #pragma unroll
    for (int ks = 0; ks < 2; ks++) {
      f16x8 a[4];
      #pragma unroll
      for (int mt = 0; mt < 4; mt++)
        a[mt] = *(const f16x8*)(Asb + (ks * 8 + mhalf * 4 + mt) * 512 + lane * 8);
      #pragma unroll
      for (int z = 0; z < 4; z++) {
        int nt = (z >> 1) * 8 + (z & 1) * 4 + ntA;
        f16x8 b = *(const f16x8*)(Bsb + (ks * 16 + nt) * 512 + lane * 8);
        #pragma unroll
        for (int mt = 0; mt < 4; mt++)
          zacc[mt][z] = __builtin_amdgcn_mfma_f32_16x16x32_f16(a[mt], b, zacc[mt][z], 0, 0, 0);
      }
    }
    if ((s & 7) == 7) {
      // epilogue for j-pair jp: bias (LDS) + gelu + contract with fp16 q.
      // Runs while the next stage's loads are still in flight.
      int jp = s >> 3;
      float bgv[4];
      #pragma unroll
      for (int z = 0; z < 4; z++) {
        int nt = (z >> 1) * 8 + (z & 1) * 4 + ntA;
        bgv[z] = bgs[jp * 256 + nt * 16 + l15];
      }
      const int d0 = 4 * jp;
      #pragma unroll
      for (int mt = 0; mt < 4; mt++) {
        #pragma unroll
        for (int r = 0; r < 4; r++) {
          int row = mhalf * 64 + mt * 16 + quad * 4 + r;
          f16x4 qp = *(const f16x4*)(Qs + row * 64 + d0);  // q[row][d0..d0+3]
          float g0 = fast_gelu(zacc[mt][0][r] + bgv[0]);
          float g1 = fast_gelu(zacc[mt][1][r] + bgv[1]);
          float g2 = fast_gelu(zacc[mt][2][r] + bgv[2]);
          float g3 = fast_gelu(zacc[mt][3][r] + bgv[3]);
          qg[mt][r] += (float)qp.x * g0 + (float)qp.y * g1 +
                       (float)qp.z * g2 + (float)qp.w * g3;
        }
      }
      #pragma unroll
      for (int i = 0; i < 4; i++)
        #pragma unroll
        for (int z = 0; z < 4; z++) zacc[i][z] = f32x4{0.f, 0.f, 0.f, 0.f};
    }
    barrier_raw();                 // protect buf[cur] before next iter's stage()
    cur ^= 1;
  }
  // write complete qg as fp16 [B][H][N][D]
  const int eb = ntA * 16;
  #pragma unroll
  for (int mt = 0; mt < 4; mt++) {
    #pragma unroll
    for (int r = 0; r < 4; r++) {
      int t = t0 + mhalf * 64 + mt * 16 + quad * 4 + r;
      int bb = t >> 10, n = t & 1023;
      qg16[(((size_t)(bb * 8 + head) * 1024) + n) * 64 + eb + l15] = f2h_bits(qg[mt][r]);
    }
  }
}

// ---------------------------------------------------------------- flash attention
// Block = (b,h,qtile64), 4 waves x 16 q-rows. R2-exact: qg read directly as
// fp16, K/V double-buffered with counted vmcnt(4) + raw barriers.
__global__ __launch_bounds__(256, 2) void attn_k(
    const u16* __restrict__ qg16, const u16* __restrict__ kb,
    const u16* __restrict__ vTb, float* __restrict__ out) {
  __shared__ __align__(16) u16 Ks[2][8 * 512];
  __shared__ __align__(16) u16 Vs[2][8 * 512];
  __shared__ __align__(16) f16 Ps[4][16 * 72];    // per-wave P, row stride 72
  const int idx = blockIdx.x;
  const int bh = idx & 31;   // b*8+h -> XCD = bh%8
  const int qt = idx >> 5;
  const int b_ = bh >> 3, h = bh & 7;
  const int tid = threadIdx.x;
  const int w = tid >> 6, lane = tid & 63, l15 = lane & 15, quad = lane >> 4;

  const u16* qgB = qg16 + (size_t)bh * 1024 * 64;
  const u16* kB  = kb  + (size_t)bh * 1024 * 64;
  const u16* vB  = vTb + (size_t)bh * 64 * 1024;

  f16x8 aq[2];
  #pragma unroll
  for (int ks = 0; ks < 2; ks++)
    aq[ks] = *(const f16x8*)(qgB + (size_t)(qt * 64 + w * 16 + l15) * 64 + ks * 32 + quad * 8);

  f32x4 o[4];
  #pragma unroll
  for (int i = 0; i < 4; i++) o[i] = f32x4{0.f, 0.f, 0.f, 0.f};
  float m_old[4], l_old[4];
  #pragma unroll
  for (int r = 0; r < 4; r++) { m_old[r] = -1e30f; l_old[r] = 0.f; }

  auto stageKV = [&](int d, int kt) {
    #pragma unroll
    for (int i = 0; i < 2; i++) {
      int cb = w * 2 + i;
      int ks = cb >> 2, nt = cb & 3;
      gll16(kB + (size_t)(kt * 64 + nt * 16 + l15) * 64 + ks * 32 + quad * 8, Ks[d] + cb * 512);
      gll16(vB + (size_t)(nt * 16 + l15) * 1024 + kt * 64 + ks * 32 + quad * 8, Vs[d] + cb * 512);
    }
  };

  stageKV(0, 0);                   // 4 loads/wave in flight
  int cur = 0;
  for (int kt = 0; kt < 16; kt++) {
    if (kt < 15) { stageKV(cur ^ 1, kt + 1); WAITV(4); }
    else         { WAITV(0); }
    barrier_raw();
    f32x4 s[4];
    #pragma unroll
    for (int nt = 0; nt < 4; nt++) s[nt] = f32x4{0.f, 0.f, 0.f, 0.f};
    #pragma unroll
    for (int ks = 0; ks < 2; ks++)
      #pragma unroll
      for (int nt = 0; nt < 4; nt++) {
        f16x8 kf = *(const f16x8*)(Ks[cur] + (ks * 4 + nt) * 512 + lane * 8);
        s[nt] = __builtin_amdgcn_mfma_f32_16x16x32_f16(aq[ks], kf, s[nt], 0, 0, 0);
      }
    float rmax[4];
    #pragma unroll
    for (int r = 0; r < 4; r++)
      rmax[r] = fmaxf(fmaxf(s[0][r], s[1][r]), fmaxf(s[2][r], s[3][r]));
    #pragma unroll
    for (int off = 1; off < 16; off <<= 1)
      #pragma unroll
      for (int r = 0; r < 4; r++)
        rmax[r] = fmaxf(rmax[r], __shfl_xor(rmax[r], off));
    float alpha[4], rsum[4];
    #pragma unroll
    for (int r = 0; r < 4; r++) {
      float mn = fmaxf(m_old[r], rmax[r]);
      alpha[r] = __expf(m_old[r] - mn);
      m_old[r] = mn;
      rsum[r] = 0.f;
    }
    #pragma unroll
    for (int nt = 0; nt < 4; nt++)
      #pragma unroll
      for (int r = 0; r < 4; r++) {
        float p = __expf(s[nt][r] - m_old[r]);
        rsum[r] += p;
        Ps[w][(quad * 4 + r) * 72 + nt * 16 + l15] = (f16)p;
      }
    #pragma unroll
    for (int off = 1; off < 16; off <<= 1)
      #pragma unroll
      for (int r = 0; r < 4; r++)
        rsum[r] += __shfl_xor(rsum[r], off);
    #pragma unroll
    for (int r = 0; r < 4; r++) l_old[r] = l_old[r] * alpha[r] + rsum[r];
    #pragma unroll
    for (int nt = 0; nt < 4; nt++)
      #pragma unroll
      for (int r = 0; r < 4; r++) o[nt][r] *= alpha[r];
    #pragma unroll
    for (int ks = 0; ks < 2; ks++) {
      f16x8 pa = *(const f16x8*)(&Ps[w][l15 * 72 + ks * 32 + quad * 8]);
      #pragma unroll
      for (int nt = 0; nt < 4; nt++) {
        f16x8 vf = *(const f16x8*)(Vs[cur] + (ks * 4 + nt) * 512 + lane * 8);
        o[nt] = __builtin_amdgcn_mfma_f32_16x16x32_f16(pa, vf, o[nt], 0, 0, 0);
      }
    }
    barrier_raw();                 // protect Ks/Vs[cur] before next stageKV
    cur ^= 1;
  }
  #pragma unroll
  for (int r = 0; r < 4; r++) {
    float inv = 1.f / l_old[r];
    int n = qt * 64 + w * 16 + quad * 4 + r;
    #pragma unroll
    for (int nt = 0; nt < 4; nt++)
      out[((size_t)(b_ * 1024 + n)) * 512 + h * 64 + nt * 16 + l15] = o[nt][r] * inv;
  }
}

// ----------------------------------------------------------------------- host
extern "C" void kernel_launch(void* const* d_in, const int* in_sizes, int n_in,
                              void* d_out, int out_size, void* d_ws, size_t ws_size,
                              hipStream_t stream) {
  const float* x  = (const float*)d_in[0];
  const float* Wq = (const float*)d_in[1];
  const float* bq = (const float*)d_in[2];
  const float* Wk = (const float*)d_in[3];
  const float* bk = (const float*)d_in[4];
  const float* Wv = (const float*)d_in[5];
  const float* bv = (const float*)d_in[6];
  const float* Wg = (const float*)d_in[7];
  const float* bg = (const float*)d_in[8];
  float* out = (float*)d_out;

  const size_t NX = (size_t)TOK * EDIM;        // 2M elems
  const size_t NWG = (size_t)GCOLS * EDIM;     // 16.8M elems
  const size_t NW = (size_t)EDIM * EDIM;       // 256K elems

  char* p = (char*)d_ws;
  u16* xf  = (u16*)p; p += NX * 2;             // x fp16
  u16* Wgt = (u16*)p; p += NWG * 2;            // Wg^T fp16 (33.5 MB)
  u16* Wqt = (u16*)p; p += NW * 2;
  u16* Wkt = (u16*)p; p += NW * 2;
  u16* Wvt = (u16*)p; p += NW * 2;
  u16* qh  = (u16*)p; p += NX * 2;             // q fp16 [B][H][N][D]
  u16* kf  = (u16*)p; p += NX * 2;             // k fp16
  u16* vT  = (u16*)p; p += NX * 2;             // v^T fp16
  u16* qg16 = (u16*)p; p += NX * 2;            // qg fp16 [B][H][N][D] (complete)

  hipLaunchKernelGGL(cast_f16_k, dim3(NX / 1024), dim3(256), 0, stream,
                     x, xf, (int)NX);
  hipLaunchKernelGGL(transpose3_f16_k, dim3(EDIM / 64, EDIM / 64, 3), dim3(256), 0, stream,
                     Wq, Wk, Wv, Wqt, Wkt, Wvt);
  hipLaunchKernelGGL(transpose_f16_wide_k, dim3(GCOLS / 64, EDIM / 64), dim3(256), 0, stream,
                     Wg, Wgt, EDIM, GCOLS);
  hipLaunchKernelGGL(qkv_gemm_k, dim3(TOK / 128, EDIM / 128, 3), dim3(256), 0, stream,
                     xf, Wqt, Wkt, Wvt, bq, bk, bv, qh, kf, vT);
  hipLaunchKernelGGL(qg_fused_k, dim3(256), dim3(512), 0, stream,
                     xf, Wgt, bg, qh, qg16);
  hipLaunchKernelGGL(attn_k, dim3(512), dim3(256), 0, stream,
                     qg16, kf, vT, out);
}